// Round 7
// baseline (761.596 us; speedup 1.0000x reference)
//
#include <hip/hip_runtime.h>
#include <hip/hip_bf16.h>
#include <math.h>

#define N1      20000          // nodes per graph
#define NT      40000          // both graphs
#define E1      640000         // edges per graph
#define ET      1280000
#define FIN_D   256
#define HID_D   512
#define TOPK    1000
#define MP1     20096          // 157 * 128 (padded M per graph)
#define NGEMM   628            // 157 x 4 blocks per 20096x512 gemm
#define AGG256  1250           // 2 slabs * 625 groups (32 nodes/group, 128B/group-slab)
#define NGRP    625            // node groups per slab

// bucketed CSR build: 157 buckets x 256 nodes, line-granular writes only
#define NB       157           // ceil(40000/256)
#define CAP      10240         // per-bucket staging capacity (mean 8153, sigma ~90)
#define BK_CHUNK 8192          // edges per bucketA block

typedef __attribute__((ext_vector_type(8))) short short8;
typedef __attribute__((ext_vector_type(4))) float floatx4;
typedef __attribute__((ext_vector_type(2))) float floatx2;
typedef unsigned int uintx4 __attribute__((ext_vector_type(4)));

__device__ __forceinline__ unsigned short f2bf(float f) {
    union { __hip_bfloat16 h; unsigned short u; } cv;
    cv.h = __float2bfloat16(f);
    return cv.u;
}
__device__ __forceinline__ float bflo(unsigned int u) {
    union { unsigned int i; float f; } c; c.i = u << 16; return c.f;
}
__device__ __forceinline__ float bfhi(unsigned int u) {
    union { unsigned int i; float f; } c; c.i = u & 0xffff0000u; return c.f;
}

// XCD-aligned GEMM block map: the 4 gemm ids sharing an A-panel are 8 apart ->
// same XCD residue under round-robin dispatch -> A panel fetched once per XCD.
__device__ __forceinline__ void gmap(int b, int& bx, int& by) {
    const int nfull = (157 / 8) * 32;      // 608
    if (b < nfull) {
        int chunk = b >> 5, w = b & 31;
        bx = (chunk << 3) + (w & 7);
        by = w >> 3;
    } else {
        int i = b - nfull;                 // 20 tail blocks: panels 152..156
        bx = 152 + i % 5;
        by = i / 5;
    }
}

// ---------------- prep bodies: convw / convx ----------------
__device__ __forceinline__ void convw_body(int bl, int K, float* tile /*32x33*/,
                                           const float* __restrict__ W,
                                           unsigned short* __restrict__ Wt) {
    int kb = K / 32;
    int k0 = (bl % kb) * 32, n0 = (bl / kb) * 32;
    int tx = threadIdx.x & 31, ty = threadIdx.x >> 5;
    for (int r = ty; r < 32; r += 8) tile[r * 33 + tx] = W[(size_t)(k0 + r) * HID_D + n0 + tx];
    __syncthreads();
    for (int r = ty; r < 32; r += 8)
        Wt[(size_t)(n0 + r) * K + k0 + tx] = f2bf(tile[tx * 33 + r]);
}
__device__ __forceinline__ void convx_body(int i, const float* __restrict__ x,
                                           unsigned char* __restrict__ x8) {
    float4 f = ((const float4*)x)[i];
    int p = __builtin_amdgcn_cvt_pk_fp8_f32(f.x, f.y, 0, false);
    p = __builtin_amdgcn_cvt_pk_fp8_f32(f.z, f.w, p, true);
    ((unsigned int*)x8)[i] = (unsigned int)p;
}

// ---------------- bucketA: LDS-staged bucket scatter ---------------------------
__device__ __forceinline__ void bucketA_body(int bb, int t,
                                             const int* __restrict__ ei1,
                                             const int* __restrict__ ei2,
                                             unsigned int* __restrict__ stageG,
                                             int* __restrict__ gcnt,
                                             unsigned int* shb) {
    unsigned int* stg   = shb;           // 8192 staged entries
    unsigned int* scn   = shb + 8192;    // 256 scan scratch
    unsigned int* hoff  = shb + 8448;    // 160 exclusive offsets
    unsigned int* hcur  = shb + 8608;    // 160 hist then cursor
    unsigned int* hbase = shb + 8768;    // 160 reserved global bases
    int e0 = bb * BK_CHUNK;
    int total = ET - e0; if (total > BK_CHUNK) total = BK_CHUNK;
    for (int i = t; i < 160; i += 256) hcur[i] = 0;
    __syncthreads();
    for (int k = 0; k < 32; ++k) {                 // pass 1: hist over dst buckets
        int e = e0 + k * 256 + t;
        if (e < ET) {
            int d = (e < E1) ? ei1[E1 + e] : (ei2[E1 + (e - E1)] + N1);
            atomicAdd(&hcur[d >> 8], 1u);
        }
    }
    __syncthreads();
    unsigned int v = (t < NB) ? hcur[t] : 0u;
    scn[t] = v; __syncthreads();
    for (int off = 1; off < 256; off <<= 1) {
        unsigned int x = (t >= off) ? scn[t - off] : 0u;
        __syncthreads(); scn[t] += x; __syncthreads();
    }
    if (t < NB) {
        unsigned int ex = scn[t] - v;
        hoff[t] = ex;
        hbase[t] = (unsigned int)atomicAdd(&gcnt[t], (int)v);
    }
    __syncthreads();
    if (t < NB) hcur[t] = hoff[t];
    __syncthreads();
    for (int k = 0; k < 32; ++k) {                 // pass 2: place into LDS by bucket
        int e = e0 + k * 256 + t;
        if (e < ET) {
            int s, d;
            if (e < E1) { s = ei1[e]; d = ei1[E1 + e]; }
            else        { int ee = e - E1; s = ei2[ee] + N1; d = ei2[E1 + ee] + N1; }
            unsigned int b8 = (unsigned int)(d >> 8);
            unsigned int pos = atomicAdd(&hcur[b8], 1u);
            stg[pos] = (unsigned int)s | ((unsigned int)(d & 255) << 16) | (b8 << 24);
        }
    }
    __syncthreads();
    for (int i = t; i < total; i += 256) {         // flush: contiguous per-bucket runs
        unsigned int e = stg[i];
        unsigned int b8 = e >> 24;
        unsigned int g = hbase[b8] + ((unsigned int)i - hoff[b8]);
        if (g < CAP) stageG[(size_t)b8 * CAP + g] = e;
    }
}

// ---------------- per-bucket counting sort body -> row_start + csr (ushort) ----
__device__ __forceinline__ void sort_body(int b, int t,
                                          const unsigned int* __restrict__ stageG,
                                          const int* __restrict__ gcnt,
                                          int* __restrict__ row_start,
                                          unsigned short* __restrict__ csr,
                                          unsigned int* shb) {
    unsigned int* cnts = shb;
    unsigned int* offs = shb + 256;
    unsigned int* cur  = shb + 512;
    unsigned int* scn  = shb + 768;
    unsigned short* outb = (unsigned short*)(shb + 1024);   // CAP ushorts = 5120 uints
    int* s_base = (int*)(shb + 6144);
    unsigned int gv = (t < NB) ? (unsigned int)gcnt[t] : 0u;
    scn[t] = gv; __syncthreads();
    for (int off = 1; off < 256; off <<= 1) {
        unsigned int x = (t >= off) ? scn[t - off] : 0u;
        __syncthreads(); scn[t] += x; __syncthreads();
    }
    if (t == b) s_base[0] = (int)(scn[t] - gv);
    cnts[t] = 0;
    __syncthreads();
    int base = s_base[0];
    int cnt = gcnt[b]; if (cnt > CAP) cnt = CAP;
    const unsigned int* src = stageG + (size_t)b * CAP;
    for (int i = t; i < cnt; i += 256) atomicAdd(&cnts[(src[i] >> 16) & 255], 1u);
    __syncthreads();
    unsigned int v = cnts[t];
    offs[t] = v; __syncthreads();
    for (int off = 1; off < 256; off <<= 1) {
        unsigned int x = (t >= off) ? offs[t - off] : 0u;
        __syncthreads(); offs[t] += x; __syncthreads();
    }
    unsigned int excl = offs[t] - v;
    cur[t] = excl;
    int node = b * 256 + t;
    if (node < NT) row_start[node] = base + (int)excl;
    if (b == 0 && t == 0) row_start[NT] = ET;
    __syncthreads();
    for (int i = t; i < cnt; i += 256) {
        unsigned int e = src[i];
        unsigned int p = atomicAdd(&cur[(e >> 16) & 255], 1u);
        outb[p] = (unsigned short)(e & 0xffffu);
    }
    __syncthreads();
    for (int i = t; i < cnt; i += 256) csr[base + i] = outb[i];
}

// ---------------- fp8 GIN aggregation body (uint4 gathers, 2-deep pipeline) ----
#define ACC4(u) do { \
    acc2[0] += __builtin_amdgcn_cvt_pk_f32_fp8((int)(u).x, false); \
    acc2[1] += __builtin_amdgcn_cvt_pk_f32_fp8((int)(u).x, true);  \
    acc2[2] += __builtin_amdgcn_cvt_pk_f32_fp8((int)(u).y, false); \
    acc2[3] += __builtin_amdgcn_cvt_pk_f32_fp8((int)(u).y, true);  \
    acc2[4] += __builtin_amdgcn_cvt_pk_f32_fp8((int)(u).z, false); \
    acc2[5] += __builtin_amdgcn_cvt_pk_f32_fp8((int)(u).z, true);  \
    acc2[6] += __builtin_amdgcn_cvt_pk_f32_fp8((int)(u).w, false); \
    acc2[7] += __builtin_amdgcn_cvt_pk_f32_fp8((int)(u).w, true);  } while (0)

template<int LPR4>   // LPR4 = uint4 per fp8 row (D/16)
__device__ __forceinline__ void agg8_body(int slab, int grp, int tid,
                                          const unsigned char* __restrict__ x8,
                                          const int* __restrict__ row_start,
                                          const unsigned short* __restrict__ csr,
                                          unsigned short* __restrict__ h, int n0) {
    int node = grp * 32 + (tid >> 3);          // exact: 625*32 = 20000
    int lanec = tid & 7;
    int chunk = slab * 8 + lanec;              // uint4 index within fp8 row
    const uint4* Xc = (const uint4*)x8 + chunk;
    floatx2 acc2[8] = {};
    uint4 v = Xc[(size_t)node * LPR4];
    ACC4(v);                                   // self term (fp8)
    int nid = n0 + node;
    int s = row_start[nid], e = row_start[nid + 1];
    int p = s;
    int nb = (e - s) >> 3;
    uint4 a0, a1, a2, a3, a4, a5, a6, a7;
    uint4 b0, b1, b2, b3, b4, b5, b6, b7;
#define LOAD8(R, P) do { \
    int q0 = (int)csr[(P) + 0] - n0, q1 = (int)csr[(P) + 1] - n0; \
    int q2 = (int)csr[(P) + 2] - n0, q3 = (int)csr[(P) + 3] - n0; \
    int q4 = (int)csr[(P) + 4] - n0, q5 = (int)csr[(P) + 5] - n0; \
    int q6 = (int)csr[(P) + 6] - n0, q7 = (int)csr[(P) + 7] - n0; \
    R##0 = Xc[(size_t)q0 * LPR4]; R##1 = Xc[(size_t)q1 * LPR4]; \
    R##2 = Xc[(size_t)q2 * LPR4]; R##3 = Xc[(size_t)q3 * LPR4]; \
    R##4 = Xc[(size_t)q4 * LPR4]; R##5 = Xc[(size_t)q5 * LPR4]; \
    R##6 = Xc[(size_t)q6 * LPR4]; R##7 = Xc[(size_t)q7 * LPR4]; } while (0)
#define ACC8(R) do { ACC4(R##0); ACC4(R##1); ACC4(R##2); ACC4(R##3); \
                     ACC4(R##4); ACC4(R##5); ACC4(R##6); ACC4(R##7); } while (0)
    if (nb > 0) {
        LOAD8(a, p); p += 8;
        int i = 1;
        for (; i + 1 < nb; i += 2) {
            LOAD8(b, p); p += 8;       // issue next 8 gathers
            ACC8(a);                    // consume current (waits only on a)
            LOAD8(a, p); p += 8;
            ACC8(b);
        }
        if (i < nb) { LOAD8(b, p); p += 8; ACC8(a); ACC8(b); }
        else        { ACC8(a); }
    }
#undef LOAD8
#undef ACC8
    for (; p + 2 <= e; p += 2) {
        int ma = (int)csr[p + 0] - n0, mb = (int)csr[p + 1] - n0;
        uint4 u0 = Xc[(size_t)ma * LPR4];
        uint4 u1 = Xc[(size_t)mb * LPR4];
        ACC4(u0); ACC4(u1);
    }
    if (p < e) {
        int ma = (int)csr[p] - n0;
        uint4 u0 = Xc[(size_t)ma * LPR4];
        ACC4(u0);
    }
    unsigned int ow[8];
#pragma unroll
    for (int i = 0; i < 8; ++i)
        ow[i] = (unsigned)f2bf(acc2[i].x) | ((unsigned)f2bf(acc2[i].y) << 16);
    uintx4 o0, o1;
    o0.x = ow[0]; o0.y = ow[1]; o0.z = ow[2]; o0.w = ow[3];
    o1.x = ow[4]; o1.y = ow[5]; o1.z = ow[6]; o1.w = ow[7];
    size_t base = ((size_t)node * LPR4 + chunk) * 2;   // bf16 row = LPR4*2 uintx4
    ((uintx4*)h)[base + 0] = o0;
    ((uintx4*)h)[base + 1] = o1;
}

// ---------------- k1: bucketA || convx(g1) -------------------------------------
__launch_bounds__(256)
__global__ void prep1_kernel(const int* __restrict__ ei1, const int* __restrict__ ei2,
                             unsigned int* __restrict__ stageG, int* __restrict__ gcnt,
                             const float* __restrict__ x1, unsigned char* __restrict__ x8) {
    __shared__ unsigned int shb[8928];
    int b = blockIdx.x;
    if (b < NB) bucketA_body(b, threadIdx.x, ei1, ei2, stageG, gcnt, shb);
    else convx_body((b - NB) * 256 + threadIdx.x, x1, x8);
}

// ---------------- k2: sort(ALL 157 buckets) || convx(g2) -----------------------
__launch_bounds__(256)
__global__ void fused_sortx(const unsigned int* __restrict__ stageG,
                            const int* __restrict__ gcnt,
                            int* __restrict__ row_start,
                            unsigned short* __restrict__ csr,
                            const float* __restrict__ x2,
                            unsigned char* __restrict__ x8g2) {
    __shared__ unsigned int shb[6152];
    int b = blockIdx.x;
    if (b < NB) sort_body(b, threadIdx.x, stageG, gcnt, row_start, csr, shb);
    else convx_body((b - NB) * 256 + threadIdx.x, x2, x8g2);
}

// ---------------- k3: agg1(g1) || 6x convw (small LDS -> full agg residency) ---
__launch_bounds__(256, 4)
__global__ void fused_aggw(const unsigned char* __restrict__ x8,
                           const int* __restrict__ row_start,
                           const unsigned short* __restrict__ csr,
                           unsigned short* __restrict__ h,
                           const float* w11, unsigned short* wt11,
                           const float* w12, unsigned short* wt12,
                           const float* w21, unsigned short* wt21,
                           const float* w22, unsigned short* wt22,
                           const float* w31, unsigned short* wt31,
                           const float* w32, unsigned short* wt32) {
    __shared__ float tile[32 * 33];
    int b = blockIdx.x;
    if (b < AGG256) {
        agg8_body<16>(b & 1, b >> 1, threadIdx.x, x8, row_start, csr, h, 0);
    } else {
        int bl = b - AGG256;
        if (bl < 128)       convw_body(bl,        FIN_D, tile, w11, wt11);
        else if (bl < 384)  convw_body(bl - 128,  HID_D, tile, w12, wt12);
        else if (bl < 640)  convw_body(bl - 384,  HID_D, tile, w21, wt21);
        else if (bl < 896)  convw_body(bl - 640,  HID_D, tile, w22, wt22);
        else if (bl < 1152) convw_body(bl - 896,  HID_D, tile, w31, wt31);
        else                convw_body(bl - 1152, HID_D, tile, w32, wt32);
    }
}

// ---------------- fp8 tile store (epilogue helper, coalesced via LDS) ----------
__device__ __forceinline__ void store_fp8_tile(int row0, int col0, int tid,
                                               unsigned short* smem,
                                               floatx4 acc[4][4], const float* __restrict__ bias,
                                               unsigned char* __restrict__ C8,
                                               int wr, int wc, int lane) {
    unsigned char* tile = (unsigned char*)smem;    // 128*128 = 16KB
    int q = lane >> 4, cn = lane & 15;
#pragma unroll
    for (int j = 0; j < 4; ++j) {
        int lcol = wc * 64 + j * 16 + cn;
        float bv = bias[col0 + lcol];
#pragma unroll
        for (int i = 0; i < 4; ++i) {
            int lrow = wr * 64 + i * 16 + q * 4;
#pragma unroll
            for (int r = 0; r < 4; ++r) {
                float vv = fmaxf(acc[i][j][r] + bv, 0.f);
                int t8 = __builtin_amdgcn_cvt_pk_fp8_f32(vv, 0.f, 0, false);
                tile[(lrow + r) * 128 + lcol] = (unsigned char)(t8 & 0xff);
            }
        }
    }
    __syncthreads();
#pragma unroll
    for (int it = 0; it < 4; ++it) {
        int idx = it * 256 + tid;
        int lrow = idx >> 3, c16 = idx & 7;
        *(uint4*)(C8 + (size_t)(row0 + lrow) * HID_D + col0 + c16 * 16) =
            *(const uint4*)(tile + lrow * 128 + c16 * 16);
    }
}

// ---------------- bf16 MFMA GEMM body, BK=32 double-buffered (32KB LDS) --------
// AUXA: cache policy for A-operand staging (0 = normal; 2 = NT/slc so streaming
// A panels don't evict the agg gather slab from L2 when co-resident in fused_k).
// Linear staging order (round-6 source-XOR swizzle broke 64B lane merge; reverted).
template<int AUXA>
__device__ __forceinline__ void gemm_body_db(int bx, int by, int tid,
                                             unsigned short* smem,
                                             const unsigned short* __restrict__ A,
                                             const unsigned short* __restrict__ Wt,
                                             const float* __restrict__ bias,
                                             unsigned short* __restrict__ C,
                                             unsigned char* __restrict__ C8, int K) {
    const int N = HID_D;
    int lane = tid & 63;
    int w = tid >> 6;
    int wr = w >> 1, wc = w & 1;
    int row0 = bx * 128;
    int col0 = by * 128;
    floatx4 acc[4][4] = {};
    int lr = tid >> 2;            // 64 rows per staging pass
    int c8 = (tid & 3) * 8;       // 4 lanes x 8 ushorts = 32-wide row
    const unsigned short* Ag = A + (size_t)row0 * K;
    const unsigned short* Bg = Wt + (size_t)col0 * K;
    int nt = K >> 5;
    {   // prologue: stage tile 0 into buffer 0
        unsigned short* As = smem;
        unsigned short* Bs = smem + 4096;
#pragma unroll
        for (int l = 0; l < 2; ++l) {
            int r = l * 64 + lr;
            __builtin_amdgcn_global_load_lds(
                (const __attribute__((address_space(1))) void*)(Ag + (size_t)r * K + c8),
                (__attribute__((address_space(3))) void*)(As + l * 2048 + tid * 8),
                16, 0, AUXA);
            __builtin_amdgcn_global_load_lds(
                (const __attribute__((address_space(1))) void*)(Bg + (size_t)r * K + c8),
                (__attribute__((address_space(3))) void*)(Bs + l * 2048 + tid * 8),
                16, 0, 0);
        }
    }
    __syncthreads();
    for (int t = 0; t < nt; ++t) {
        unsigned short* As = smem + ((t & 1) ? 8192 : 0);
        unsigned short* Bs = As + 4096;
        if (t + 1 < nt) {         // issue next-tile loads into the other buffer
            unsigned short* An = smem + ((t & 1) ? 0 : 8192);
            unsigned short* Bn = An + 4096;
            int kt = (t + 1) << 5;
#pragma unroll
            for (int l = 0; l < 2; ++l) {
                int r = l * 64 + lr;
                __builtin_amdgcn_global_load_lds(
                    (const __attribute__((address_space(1))) void*)(Ag + (size_t)r * K + kt + c8),
                    (__attribute__((address_space(3))) void*)(An + l * 2048 + tid * 8),
                    16, 0, AUXA);
                __builtin_amdgcn_global_load_lds(
                    (const __attribute__((address_space(1))) void*)(Bg + (size_t)r * K + kt + c8),
                    (__attribute__((address_space(3))) void*)(Bn + l * 2048 + tid * 8),
                    16, 0, 0);
            }
        }
        short8 af[4], bf[4];
        int q8 = (lane >> 4) * 8;
#pragma unroll
        for (int i = 0; i < 4; ++i) {
            int m = wr * 64 + i * 16 + (lane & 15);
            af[i] = *(const short8*)&As[m * 32 + q8];
            int n = wc * 64 + i * 16 + (lane & 15);
            bf[i] = *(const short8*)&Bs[n * 32 + q8];
        }
#pragma unroll
        for (int i = 0; i < 4; ++i)
#pragma unroll
            for (int j = 0; j < 4; ++j)
                acc[i][j] = __builtin_amdgcn_mfma_f32_16x16x32_bf16(af[i], bf[j], acc[i][j], 0, 0, 0);
        __syncthreads();          // drains vmcnt: next buffer ready; cur buffer free
    }
    if (C8) {
        store_fp8_tile(row0, col0, tid, smem, acc, bias, C8, wr, wc, lane);
        return;
    }
    int q = lane >> 4;
    int cn = lane & 15;
#pragma unroll
    for (int j = 0; j < 4; ++j) {
        int col = col0 + wc * 64 + j * 16 + cn;
        float bv = bias[col];
#pragma unroll
        for (int i = 0; i < 4; ++i) {
            int rowb = row0 + wr * 64 + i * 16 + q * 4;
#pragma unroll
            for (int r = 0; r < 4; ++r) {
                float vv = fmaxf(acc[i][j][r] + bv, 0.f);
                C[(size_t)(rowb + r) * N + col] = f2bf(vv);
            }
        }
    }
}

// two independent gemms (different graphs) in one launch
__launch_bounds__(256)
__global__ void gemm_pair(const unsigned short* __restrict__ A1,
                          const unsigned short* __restrict__ W1,
                          const float* __restrict__ b1,
                          unsigned short* __restrict__ C1, unsigned char* C81, int K1,
                          const unsigned short* __restrict__ A2,
                          const unsigned short* __restrict__ W2,
                          const float* __restrict__ b2,
                          unsigned short* __restrict__ C2, unsigned char* C82, int K2) {
    __shared__ unsigned short smem[16384];
    int b = blockIdx.x;
    int bx, by;
    if (b < NGEMM) {
        gmap(b, bx, by);
        gemm_body_db<0>(bx, by, threadIdx.x, smem, A1, W1, b1, C1, C81, K1);
    } else {
        gmap(b - NGEMM, bx, by);
        gemm_body_db<0>(bx, by, threadIdx.x, smem, A2, W2, b2, C2, C82, K2);
    }
}

// ---------------- fused: XCD-aligned gemm/agg interleave -----------------------
// Period = 8 gemm + 8*NSLAB agg blocks. Per XCD (b mod 8): 1 gemm : NSLAB agg
// co-resident, so agg latency hides under MFMA and vice versa. Slab from the
// position within the period keeps slab<->XCD pinning; gemm panel-mates stay
// 8 ids apart -> same XCD. A staged with NT so it can't evict the gather slab.
template<int LPR4, int NSLAB>
__launch_bounds__(256)
__global__ void fused_k(const unsigned short* __restrict__ A,
                        const unsigned short* __restrict__ Wt,
                        const float* __restrict__ bias,
                        unsigned short* __restrict__ C, unsigned char* C8, int K,
                        const unsigned char* __restrict__ x8,
                        const int* __restrict__ row_start,
                        const unsigned short* __restrict__ csr,
                        unsigned short* __restrict__ h, int n0) {
    __shared__ unsigned short smem[16384];
    const int PERIOD = 8 + 8 * NSLAB;
    const int LGNS = (NSLAB == 4) ? 2 : 1;
    int b = blockIdx.x;
    int k = b / PERIOD, j = b % PERIOD;
    if (j < 8) {
        int g = k * 8 + j;
        if (g < NGEMM) {
            int bx, by;
            gmap(g, bx, by);
            gemm_body_db<2>(bx, by, threadIdx.x, smem, A, Wt, bias, C, C8, K);
        }
    } else {
        int ja = j - 8;
        int slab = ja & (NSLAB - 1);
        int grp = k * 8 + (ja >> LGNS);
        if (grp < NGRP)
            agg8_body<LPR4>(slab, grp, threadIdx.x, x8, row_start, csr, h, n0);
    }
}
#define GRID_K2  (79 * 24)     // fused_k<16,2> grid
#define GRID_K4  (79 * 40)     // fused_k<32,4> grid

// ---------------- final linear [M,512]bf16 @ [512,2]fp32 + b ----------------
__device__ __forceinline__ void lin_body(int bb, int tid, const unsigned short* __restrict__ A,
                                         const float* __restrict__ w, const float* __restrict__ b,
                                         float* __restrict__ o, int M) {
    int wave = tid >> 6;
    int lane = tid & 63;
    int row = bb * 4 + wave;
    if (row >= M) return;
    const uint4* Ar = (const uint4*)(A + (size_t)row * 512);
    uint4 u = Ar[lane];
    float f[8];
    f[0] = bflo(u.x); f[1] = bfhi(u.x); f[2] = bflo(u.y); f[3] = bfhi(u.y);
    f[4] = bflo(u.z); f[5] = bfhi(u.z); f[6] = bflo(u.w); f[7] = bfhi(u.w);
    float s0 = 0.f, s1 = 0.f;
#pragma unroll
    for (int j = 0; j < 8; ++j) {
        int base = (lane * 8 + j) * 2;
        s0 = fmaf(f[j], w[base + 0], s0);
        s1 = fmaf(f[j], w[base + 1], s1);
    }
#pragma unroll
    for (int off = 32; off > 0; off >>= 1) {
        s0 += __shfl_down(s0, off, 64);
        s1 += __shfl_down(s1, off, 64);
    }
    if (lane == 0) { o[row * 2] = s0 + b[0]; o[row * 2 + 1] = s1 + b[1]; }
}

// s10: G32(g2) || lin(g1)
__launch_bounds__(256)
__global__ void fused_gemmlin(const unsigned short* __restrict__ A,
                              const unsigned short* __restrict__ Wt,
                              const float* __restrict__ bias,
                              unsigned short* __restrict__ C, int K,
                              const unsigned short* __restrict__ L,
                              const float* __restrict__ lw, const float* __restrict__ lb,
                              float* __restrict__ o) {
    __shared__ unsigned short smem[16384];
    int b = blockIdx.x;
    if (b < NGEMM) {
        int bx, by;
        gmap(b, bx, by);
        gemm_body_db<0>(bx, by, threadIdx.x, smem, A, Wt, bias, C, nullptr, K);
    } else {
        lin_body(b - NGEMM, threadIdx.x, L, lw, lb, o, N1);
    }
}

// s11: lin(g2) + dist
__global__ void lin_dist_kernel(const unsigned short* __restrict__ A,
                                const float* __restrict__ w, const float* __restrict__ b,
                                const float* __restrict__ o1,
                                float* __restrict__ o2out,
                                float* __restrict__ dist) {
    int tid = threadIdx.x;
    int wave = tid >> 6;
    int lane = tid & 63;
    int row = blockIdx.x * 4 + wave;
    if (row >= N1) return;
    const uint4* Ar = (const uint4*)(A + (size_t)row * 512);
    uint4 u = Ar[lane];
    float f[8];
    f[0] = bflo(u.x); f[1] = bfhi(u.x); f[2] = bflo(u.y); f[3] = bfhi(u.y);
    f[4] = bflo(u.z); f[5] = bfhi(u.z); f[6] = bflo(u.w); f[7] = bfhi(u.w);
    float s0 = 0.f, s1 = 0.f;
#pragma unroll
    for (int j = 0; j < 8; ++j) {
        int base = (lane * 8 + j) * 2;
        s0 = fmaf(f[j], w[base + 0], s0);
        s1 = fmaf(f[j], w[base + 1], s1);
    }
#pragma unroll
    for (int off = 32; off > 0; off >>= 1) {
        s0 += __shfl_down(s0, off, 64);
        s1 += __shfl_down(s1, off, 64);
    }
    if (lane == 0) {
        float vx = s0 + b[0], vy = s1 + b[1];
        o2out[row * 2] = vx; o2out[row * 2 + 1] = vy;
        float2 a = ((const float2*)o1)[row];
        float d0 = a.x - vx + 1e-6f, d1 = a.y - vy + 1e-6f;
        dist[row] = sqrtf(d0 * d0 + d1 * d1);
    }
}

// LDS-privatized histogram
#define HBLK 20
#define HPB  1000
__launch_bounds__(256)
__global__ void hist_lds_kernel(const float* __restrict__ dist, int* __restrict__ hist) {
    __shared__ int lh[4096];
    int t = threadIdx.x;
    for (int i = t; i < 4096; i += 256) lh[i] = 0;
    __syncthreads();
    int base = blockIdx.x * HPB;
    for (int i = t; i < HPB; i += 256) {
        int idx = base + i;
        if (idx < N1) atomicAdd(&lh[__float_as_uint(dist[idx]) >> 19], 1);
    }
    __syncthreads();
    for (int i = t; i < 4096; i += 256) {
        int v = lh[i];
        if (v) atomicAdd(&hist[i], v);
    }
}

// ---------------- radix-select top-k ----------------
__global__ void selk_kernel(const int* __restrict__ hist, int* __restrict__ selout) {
    __shared__ int tile[256];
    int t = threadIdx.x;
    int running = 0;
    for (int tb = 0; tb < 16; ++tb) {
        int idx = 4095 - (tb * 256 + t);
        int v = hist[idx];
        tile[t] = v;
        __syncthreads();
        for (int off = 1; off < 256; off <<= 1) {
            int x = (t >= off) ? tile[t - off] : 0;
            __syncthreads();
            tile[t] += x;
            __syncthreads();
        }
        int incl = running + tile[t];
        if (incl >= TOPK && incl - v < TOPK) selout[0] = idx;
        running += tile[255];
        __syncthreads();
        if (running >= TOPK) break;
    }
}

__global__ void compact_kernel(const float* __restrict__ dist, const int* __restrict__ selout,
                               int* __restrict__ nc, float* __restrict__ cd, int* __restrict__ ci) {
    int i = blockIdx.x * blockDim.x + threadIdx.x;
    if (i >= N1) return;
    float d = dist[i];
    int b = (int)(__float_as_uint(d) >> 19);
    if (b >= selout[0]) {
        int p = atomicAdd(nc, 1);
        cd[p] = d;
        ci[p] = i;
    }
}

#define CCH 2048
__global__ void rankc_kernel(const float* __restrict__ cd, const int* __restrict__ ci,
                             const int* __restrict__ nc_p, float* __restrict__ vals) {
    __shared__ float ds[CCH];
    __shared__ int   di_[CCH];
    int nc = *nc_p;
    if (blockIdx.x * 256 >= nc) return;
    int t = threadIdx.x;
    int q = blockIdx.x * 256 + t;
    float dq = 0.f; int iq = 0;
    if (q < nc) { dq = cd[q]; iq = ci[q]; }
    int cnt = 0;
    for (int c0 = 0; c0 < nc; c0 += CCH) {
        int lim = min(CCH, nc - c0);
        for (int j = t; j < lim; j += 256) { ds[j] = cd[c0 + j]; di_[j] = ci[c0 + j]; }
        __syncthreads();
        if (q < nc) {
            for (int j = 0; j < lim; ++j) {
                float dj = ds[j];
                cnt += (dj > dq) || (dj == dq && di_[j] < iq);
            }
        }
        __syncthreads();
    }
    if (q < nc && cnt < TOPK) vals[cnt] = dq;
}

// ---------------- head MLP (fc1 split 4-way) ----------------
__launch_bounds__(512)
__global__ void head_kernel(const float* __restrict__ vals,
                            const float* __restrict__ fc1_w, const float* __restrict__ fc1_b,
                            const float* __restrict__ ln1_g, const float* __restrict__ ln1_b,
                            const float* __restrict__ fc2_w, const float* __restrict__ fc2_b,
                            const float* __restrict__ ln2_g, const float* __restrict__ ln2_b,
                            const float* __restrict__ fc3_w, const float* __restrict__ fc3_b,
                            float* __restrict__ out) {
    __shared__ float sv[TOPK];
    __shared__ float a1[128];
    __shared__ float red[512];
    __shared__ float s_m, s_r;
    int t = threadIdx.x;
    for (int i = t; i < TOPK; i += 512) sv[i] = vals[i];
    __syncthreads();
    int g = t >> 7, c = t & 127;
    float part = 0.f;
    for (int j = g * 250; j < g * 250 + 250; ++j)
        part = fmaf(sv[j], fc1_w[j * 128 + c], part);
    red[t] = part;
    __syncthreads();
    float h1 = 0.f;
    if (t < 128) h1 = fc1_b[t] + red[t] + red[t + 128] + red[t + 256] + red[t + 384];
    __syncthreads();
    red[t] = (t < 128) ? h1 : 0.f; __syncthreads();
    for (int s = 256; s > 0; s >>= 1) { if (t < s) red[t] += red[t + s]; __syncthreads(); }
    if (t == 0) s_m = red[0] / 128.f;
    __syncthreads();
    float m1 = s_m;
    float dv = (t < 128) ? (h1 - m1) : 0.f;
    red[t] = dv * dv; __syncthreads();
    for (int s = 256; s > 0; s >>= 1) { if (t < s) red[t] += red[t + s]; __syncthreads(); }
    if (t == 0) s_r = rsqrtf(red[0] / 128.f + 1e-5f);
    __syncthreads();
    float r1 = s_r;
    if (t < 128) a1[t] = fmaxf((h1 - m1) * r1 * ln1_g[t] + ln1_b[t], 0.f);
    __syncthreads();
    float h2 = fc2_b[t];
    for (int j = 0; j < 128; ++j) h2 = fmaf(a1[j], fc2_w[j * 512 + t], h2);
    red[t] = h2; __syncthreads();
    for (int s = 256; s > 0; s >>= 1) { if (t < s) red[t] += red[t + s]; __syncthreads(); }
    if (t == 0) s_m = red[0] / 512.f;
    __syncthreads();
    float m2 = s_m;
    float d2 = h2 - m2;
    red[t] = d2 * d2; __syncthreads();
    for (int s = 256; s > 0; s >>= 1) { if (t < s) red[t] += red[t + s]; __syncthreads(); }
    if (t == 0) s_r = rsqrtf(red[0] / 512.f + 1e-5f);
    __syncthreads();
    float r2 = s_r;
    float y2 = fmaxf((h2 - m2) * r2 * ln2_g[t] + ln2_b[t], 0.f);
    red[t] = y2 * fc3_w[t]; __syncthreads();
    for (int s = 256; s > 0; s >>= 1) { if (t < s) red[t] += red[t + s]; __syncthreads(); }
    if (t == 0) out[0] = 1.f / (1.f + expf(-(red[0] + fc3_b[0])));
}

extern "C" void kernel_launch(void* const* d_in, const int* in_sizes, int n_in,
                              void* d_out, int out_size, void* d_ws, size_t ws_size,
                              hipStream_t stream) {
    const float* x1   = (const float*)d_in[0];
    const int*   ei1  = (const int*)d_in[1];
    const float* x2   = (const float*)d_in[2];
    const int*   ei2  = (const int*)d_in[3];
    const float* w11  = (const float*)d_in[4];
    const float* b11  = (const float*)d_in[5];
    const float* w12  = (const float*)d_in[6];
    const float* b12  = (const float*)d_in[7];
    const float* w21  = (const float*)d_in[8];
    const float* b21  = (const float*)d_in[9];
    const float* w22  = (const float*)d_in[10];
    const float* b22  = (const float*)d_in[11];
    const float* w31  = (const float*)d_in[12];
    const float* b31  = (const float*)d_in[13];
    const float* w32  = (const float*)d_in[14];
    const float* b32  = (const float*)d_in[15];
    const float* lw   = (const float*)d_in[16];
    const float* lb   = (const float*)d_in[17];
    const float* fc1w = (const float*)d_in[18];
    const float* fc1b = (const float*)d_in[19];
    const float* ln1g = (const float*)d_in[20];
    const float* ln1b = (const float*)d_in[21];
    const float* fc2w = (const float*)d_in[22];
    const float* fc2b = (const float*)d_in[23];
    const float* ln2g = (const float*)d_in[24];
    const float* ln2b = (const float*)d_in[25];
    const float* fc3w = (const float*)d_in[26];
    const float* fc3b = (const float*)d_in[27];

    char* ws = (char*)d_ws;
    size_t off = 0;
    auto alloc = [&](size_t bytes) -> void* {
        void* p = ws + off;
        off += (bytes + 255) & ~(size_t)255;
        return p;
    };
    unsigned char*  XB8 = (unsigned char*)alloc((size_t)NT * FIN_D);       // fp8 inputs
    unsigned short* H0a = (unsigned short*)alloc((size_t)MP1 * HID_D * 2);
    unsigned short* H1a = (unsigned short*)alloc((size_t)MP1 * HID_D * 2);
    unsigned short* H0b = (unsigned short*)alloc((size_t)MP1 * HID_D * 2);
    unsigned short* H1b = (unsigned short*)alloc((size_t)MP1 * HID_D * 2);
    unsigned char*  F8a = (unsigned char*)alloc((size_t)MP1 * HID_D);      // fp8 agg tables
    unsigned char*  F8b = (unsigned char*)alloc((size_t)MP1 * HID_D);
    unsigned short* wt11 = (unsigned short*)alloc((size_t)HID_D * FIN_D * 2);
    unsigned short* wt12 = (unsigned short*)alloc((size_t)HID_D * HID_D * 2);
    unsigned short* wt21 = (unsigned short*)alloc((size_t)HID_D * HID_D * 2);
    unsigned short* wt22 = (unsigned short*)alloc((size_t)HID_D * HID_D * 2);
    unsigned short* wt31 = (unsigned short*)alloc((size_t)HID_D * HID_D * 2);
    unsigned short* wt32 = (unsigned short*)alloc((size_t)HID_D * HID_D * 2);
    float* o         = (float*)alloc((size_t)NT * 2 * 4);
    float* dist      = (float*)alloc((size_t)N1 * 4);
    float* vals      = (float*)alloc((size_t)TOPK * 4);
    int*   row_start = (int*)alloc((size_t)(NT + 1) * 4);
    unsigned short* csr16 = (unsigned short*)alloc((size_t)ET * 2);
    unsigned int* stageG  = (unsigned int*)alloc((size_t)NB * CAP * 4);    // 6.4MB bucket staging
    int*   gcnt      = (int*)alloc((size_t)160 * 4);
    int*   selblk    = (int*)alloc((size_t)(4096 + 64) * 4);
    int*   hist      = selblk;
    int*   nc        = selblk + 4096;
    int*   selout    = (int*)alloc(2 * 4);
    float* cd        = (float*)alloc((size_t)N1 * 4);
    int*   ci        = (int*)alloc((size_t)N1 * 4);

    const unsigned char* XB8g2 = XB8 + (size_t)N1 * FIN_D;

    // ---- pipelined prep: nothing latency-bound runs naked ----
    hipMemsetAsync(gcnt, 0, 160 * sizeof(int), stream);
    hipMemsetAsync(selblk, 0, (4096 + 64) * sizeof(int), stream);
    // k1: bucketA || convx(g1)
    prep1_kernel<<<NB + 5000, 256, 0, stream>>>(ei1, ei2, stageG, gcnt, x1, XB8);
    // k2: sort(all buckets) || convx(g2)
    fused_sortx<<<NB + 5000, 256, 0, stream>>>(stageG, gcnt, row_start, csr16,
                                               x2, (unsigned char*)XB8g2);
    // k3: agg1(g1) || 6x convw  (4.2KB LDS -> full agg residency)
    fused_aggw<<<AGG256 + 1408, 256, 0, stream>>>(
        XB8, row_start, csr16, H0a,
        w11, wt11, w12, wt12, w21, wt21, w22, wt22, w31, wt31, w32, wt32);

    // ---- staggered two-graph pipeline (interleaved gemm/agg co-tenancy) ----
    // s2: G11(g1) bf16 || agg1(g2) fp8
    fused_k<16, 2><<<GRID_K2, 256, 0, stream>>>(H0a, wt11, b11, H1a, nullptr, FIN_D,
                                                XB8g2, row_start, csr16, H0b, N1);
    // s3: G12(g1)->fp8 F8a + G11(g2)->bf16 H1b
    gemm_pair<<<2 * NGEMM, 256, 0, stream>>>(H1a, wt12, b12, nullptr, F8a, HID_D,
                                             H0b, wt11, b11, H1b, nullptr, FIN_D);
    // s4: G12(g2)->fp8 F8b || agg2(g1): F8a -> H1a
    fused_k<32, 4><<<GRID_K4, 256, 0, stream>>>(H1b, wt12, b12, nullptr, F8b, HID_D,
                                                F8a, row_start, csr16, H1a, 0);
    // s5: G21(g1): H1a -> H0a || agg2(g2): F8b -> H1b
    fused_k<32, 4><<<GRID_K4, 256, 0, stream>>>(H1a, wt21, b21, H0a, nullptr, HID_D,
                                                F8b, row_start, csr16, H1b, N1);
    // s6: G22(g1)->fp8 F8a + G21(g2): H1b -> H0b
    gemm_pair<<<2 * NGEMM, 256, 0, stream>>>(H0a, wt22, b22, nullptr, F8a, HID_D,
                                             H1b, wt21, b21, H0b, nullptr, HID_D);
    // s7: G22(g2)->fp8 F8b || agg3(g1): F8a -> H1a
    fused_k<32, 4><<<GRID_K4, 256, 0, stream>>>(H0b, wt22, b22, nullptr, F8b, HID_D,
                                                F8a, row_start, csr16, H1a, 0);
    // s8: G31(g1): H1a -> H0a || agg3(g2): F8b -> H1b
    fused_k<32, 4><<<GRID_K4, 256, 0, stream>>>(H1a, wt31, b31, H0a, nullptr, HID_D,
                                                F8b, row_start, csr16, H1b, N1);
    // s9: G32(g1): H0a -> H1a + G31(g2): H1b -> H0b
    gemm_pair<<<2 * NGEMM, 256, 0, stream>>>(H0a, wt32, b32, H1a, nullptr, HID_D,
                                             H1b, wt31, b31, H0b, nullptr, HID_D);
    // s10: G32(g2): H0b -> H1b || lin(g1) reads H1a
    fused_gemmlin<<<NGEMM + (N1 + 3) / 4, 256, 0, stream>>>(H0b, wt32, b32, H1b, HID_D,
                                                            H1a, lw, lb, o);
    // s11: lin(g2) + dist
    lin_dist_kernel<<<(N1 + 3) / 4, 256, 0, stream>>>(H1b, lw, lb, o,
                                                      o + 2 * (size_t)N1, dist);
    // s12: LDS-privatized histogram
    hist_lds_kernel<<<HBLK, 256, 0, stream>>>(dist, hist);

    // ---- radix-select top-k + head ----
    selk_kernel<<<1, 256, 0, stream>>>(hist, selout);
    compact_kernel<<<(N1 + 255) / 256, 256, 0, stream>>>(dist, selout, nc, cd, ci);
    rankc_kernel<<<(N1 + 255) / 256, 256, 0, stream>>>(cd, ci, nc, vals);
    head_kernel<<<1, 512, 0, stream>>>(vals, fc1w, fc1b, ln1g, ln1b,
                                       fc2w, fc2b, ln2g, ln2b, fc3w, fc3b,
                                       (float*)d_out);
}

// Round 8
// 683.710 us; speedup vs baseline: 1.1139x; 1.1139x over previous
//
#include <hip/hip_runtime.h>
#include <hip/hip_bf16.h>
#include <math.h>

#define N1      20000          // nodes per graph
#define NT      40000          // both graphs
#define E1      640000         // edges per graph
#define ET      1280000
#define FIN_D   256
#define HID_D   512
#define TOPK    1000
#define MP1     20096          // 157 * 128 (padded M per graph)
#define NGEMM   628            // 157 x 4 blocks per 20096x512 gemm
#define AGG256  1250           // 2 slabs * 625 groups (32 nodes/group, 128B/group-slab)
#define AGG512  2500           // 4 slabs * 625 groups

// bucketed CSR build: 157 buckets x 256 nodes, line-granular writes only
#define NB       157           // ceil(40000/256)
#define CAP      10240         // per-bucket staging capacity (mean 8153, sigma ~90)
#define BK_CHUNK 8192          // edges per bucketA block

typedef __attribute__((ext_vector_type(8))) short short8;
typedef __attribute__((ext_vector_type(4))) float floatx4;
typedef __attribute__((ext_vector_type(2))) float floatx2;
typedef unsigned int uintx4 __attribute__((ext_vector_type(4)));

__device__ __forceinline__ unsigned short f2bf(float f) {
    union { __hip_bfloat16 h; unsigned short u; } cv;
    cv.h = __float2bfloat16(f);
    return cv.u;
}
__device__ __forceinline__ float bflo(unsigned int u) {
    union { unsigned int i; float f; } c; c.i = u << 16; return c.f;
}
__device__ __forceinline__ float bfhi(unsigned int u) {
    union { unsigned int i; float f; } c; c.i = u & 0xffff0000u; return c.f;
}

// XCD-aligned GEMM block map: the 4 gemm ids sharing an A-panel are 8 apart ->
// same XCD residue under round-robin dispatch -> A panel fetched once per XCD.
__device__ __forceinline__ void gmap(int b, int& bx, int& by) {
    const int nfull = (157 / 8) * 32;      // 608
    if (b < nfull) {
        int chunk = b >> 5, w = b & 31;
        bx = (chunk << 3) + (w & 7);
        by = w >> 3;
    } else {
        int i = b - nfull;                 // 20 tail blocks: panels 152..156
        bx = 152 + i % 5;
        by = i / 5;
    }
}

// ---------------- prep bodies: convw / convx ----------------
__device__ __forceinline__ void convw_body(int bl, int K, float* tile /*32x33*/,
                                           const float* __restrict__ W,
                                           unsigned short* __restrict__ Wt) {
    int kb = K / 32;
    int k0 = (bl % kb) * 32, n0 = (bl / kb) * 32;
    int tx = threadIdx.x & 31, ty = threadIdx.x >> 5;
    for (int r = ty; r < 32; r += 8) tile[r * 33 + tx] = W[(size_t)(k0 + r) * HID_D + n0 + tx];
    __syncthreads();
    for (int r = ty; r < 32; r += 8)
        Wt[(size_t)(n0 + r) * K + k0 + tx] = f2bf(tile[tx * 33 + r]);
}
__device__ __forceinline__ void convx_body(int i, const float* __restrict__ x,
                                           unsigned char* __restrict__ x8) {
    float4 f = ((const float4*)x)[i];
    int p = __builtin_amdgcn_cvt_pk_fp8_f32(f.x, f.y, 0, false);
    p = __builtin_amdgcn_cvt_pk_fp8_f32(f.z, f.w, p, true);
    ((unsigned int*)x8)[i] = (unsigned int)p;
}

// ---------------- bucketA: LDS-staged bucket scatter ---------------------------
__device__ __forceinline__ void bucketA_body(int bb, int t,
                                             const int* __restrict__ ei1,
                                             const int* __restrict__ ei2,
                                             unsigned int* __restrict__ stageG,
                                             int* __restrict__ gcnt,
                                             unsigned int* shb) {
    unsigned int* stg   = shb;           // 8192 staged entries
    unsigned int* scn   = shb + 8192;    // 256 scan scratch
    unsigned int* hoff  = shb + 8448;    // 160 exclusive offsets
    unsigned int* hcur  = shb + 8608;    // 160 hist then cursor
    unsigned int* hbase = shb + 8768;    // 160 reserved global bases
    int e0 = bb * BK_CHUNK;
    int total = ET - e0; if (total > BK_CHUNK) total = BK_CHUNK;
    for (int i = t; i < 160; i += 256) hcur[i] = 0;
    __syncthreads();
    for (int k = 0; k < 32; ++k) {                 // pass 1: hist over dst buckets
        int e = e0 + k * 256 + t;
        if (e < ET) {
            int d = (e < E1) ? ei1[E1 + e] : (ei2[E1 + (e - E1)] + N1);
            atomicAdd(&hcur[d >> 8], 1u);
        }
    }
    __syncthreads();
    unsigned int v = (t < NB) ? hcur[t] : 0u;
    scn[t] = v; __syncthreads();
    for (int off = 1; off < 256; off <<= 1) {
        unsigned int x = (t >= off) ? scn[t - off] : 0u;
        __syncthreads(); scn[t] += x; __syncthreads();
    }
    if (t < NB) {
        unsigned int ex = scn[t] - v;
        hoff[t] = ex;
        hbase[t] = (unsigned int)atomicAdd(&gcnt[t], (int)v);
    }
    __syncthreads();
    if (t < NB) hcur[t] = hoff[t];
    __syncthreads();
    for (int k = 0; k < 32; ++k) {                 // pass 2: place into LDS by bucket
        int e = e0 + k * 256 + t;
        if (e < ET) {
            int s, d;
            if (e < E1) { s = ei1[e]; d = ei1[E1 + e]; }
            else        { int ee = e - E1; s = ei2[ee] + N1; d = ei2[E1 + ee] + N1; }
            unsigned int b8 = (unsigned int)(d >> 8);
            unsigned int pos = atomicAdd(&hcur[b8], 1u);
            stg[pos] = (unsigned int)s | ((unsigned int)(d & 255) << 16) | (b8 << 24);
        }
    }
    __syncthreads();
    for (int i = t; i < total; i += 256) {         // flush: contiguous per-bucket runs
        unsigned int e = stg[i];
        unsigned int b8 = e >> 24;
        unsigned int g = hbase[b8] + ((unsigned int)i - hoff[b8]);
        if (g < CAP) stageG[(size_t)b8 * CAP + g] = e;
    }
}

// ---------------- per-bucket counting sort body -> row_start + csr (ushort) ----
__device__ __forceinline__ void sort_body(int b, int t,
                                          const unsigned int* __restrict__ stageG,
                                          const int* __restrict__ gcnt,
                                          int* __restrict__ row_start,
                                          unsigned short* __restrict__ csr,
                                          unsigned int* shb) {
    unsigned int* cnts = shb;
    unsigned int* offs = shb + 256;
    unsigned int* cur  = shb + 512;
    unsigned int* scn  = shb + 768;
    unsigned short* outb = (unsigned short*)(shb + 1024);   // CAP ushorts = 5120 uints
    int* s_base = (int*)(shb + 6144);
    unsigned int gv = (t < NB) ? (unsigned int)gcnt[t] : 0u;
    scn[t] = gv; __syncthreads();
    for (int off = 1; off < 256; off <<= 1) {
        unsigned int x = (t >= off) ? scn[t - off] : 0u;
        __syncthreads(); scn[t] += x; __syncthreads();
    }
    if (t == b) s_base[0] = (int)(scn[t] - gv);
    cnts[t] = 0;
    __syncthreads();
    int base = s_base[0];
    int cnt = gcnt[b]; if (cnt > CAP) cnt = CAP;
    const unsigned int* src = stageG + (size_t)b * CAP;
    for (int i = t; i < cnt; i += 256) atomicAdd(&cnts[(src[i] >> 16) & 255], 1u);
    __syncthreads();
    unsigned int v = cnts[t];
    offs[t] = v; __syncthreads();
    for (int off = 1; off < 256; off <<= 1) {
        unsigned int x = (t >= off) ? offs[t - off] : 0u;
        __syncthreads(); offs[t] += x; __syncthreads();
    }
    unsigned int excl = offs[t] - v;
    cur[t] = excl;
    int node = b * 256 + t;
    if (node < NT) row_start[node] = base + (int)excl;
    if (b == 0 && t == 0) row_start[NT] = ET;
    __syncthreads();
    for (int i = t; i < cnt; i += 256) {
        unsigned int e = src[i];
        unsigned int p = atomicAdd(&cur[(e >> 16) & 255], 1u);
        outb[p] = (unsigned short)(e & 0xffffu);
    }
    __syncthreads();
    for (int i = t; i < cnt; i += 256) csr[base + i] = outb[i];
}

// ---------------- fp8 GIN aggregation body (uint4 gathers, 2-deep pipeline) ----
#define ACC4(u) do { \
    acc2[0] += __builtin_amdgcn_cvt_pk_f32_fp8((int)(u).x, false); \
    acc2[1] += __builtin_amdgcn_cvt_pk_f32_fp8((int)(u).x, true);  \
    acc2[2] += __builtin_amdgcn_cvt_pk_f32_fp8((int)(u).y, false); \
    acc2[3] += __builtin_amdgcn_cvt_pk_f32_fp8((int)(u).y, true);  \
    acc2[4] += __builtin_amdgcn_cvt_pk_f32_fp8((int)(u).z, false); \
    acc2[5] += __builtin_amdgcn_cvt_pk_f32_fp8((int)(u).z, true);  \
    acc2[6] += __builtin_amdgcn_cvt_pk_f32_fp8((int)(u).w, false); \
    acc2[7] += __builtin_amdgcn_cvt_pk_f32_fp8((int)(u).w, true);  } while (0)

template<int LPR4, int NSLAB>   // LPR4 = uint4 per fp8 row (D/16); NSLAB = D/128
__device__ __forceinline__ void agg8_body(int ab, int tid,
                                          const unsigned char* __restrict__ x8,
                                          const int* __restrict__ row_start,
                                          const unsigned short* __restrict__ csr,
                                          unsigned short* __restrict__ h, int n0) {
    int slab = ab & (NSLAB - 1);               // XCD-pinned (blockIdx round-robin)
    int grp  = ab / NSLAB;                     // 0..624
    int node = grp * 32 + (tid >> 3);          // exact: 625*32 = 20000
    int lanec = tid & 7;
    int chunk = slab * 8 + lanec;              // uint4 index within fp8 row
    const uint4* Xc = (const uint4*)x8 + chunk;
    floatx2 acc2[8] = {};
    uint4 v = Xc[(size_t)node * LPR4];
    ACC4(v);                                   // self term (fp8)
    int nid = n0 + node;
    int s = row_start[nid], e = row_start[nid + 1];
    int p = s;
    int nb = (e - s) >> 3;
    uint4 a0, a1, a2, a3, a4, a5, a6, a7;
    uint4 b0, b1, b2, b3, b4, b5, b6, b7;
#define LOAD8(R, P) do { \
    int q0 = (int)csr[(P) + 0] - n0, q1 = (int)csr[(P) + 1] - n0; \
    int q2 = (int)csr[(P) + 2] - n0, q3 = (int)csr[(P) + 3] - n0; \
    int q4 = (int)csr[(P) + 4] - n0, q5 = (int)csr[(P) + 5] - n0; \
    int q6 = (int)csr[(P) + 6] - n0, q7 = (int)csr[(P) + 7] - n0; \
    R##0 = Xc[(size_t)q0 * LPR4]; R##1 = Xc[(size_t)q1 * LPR4]; \
    R##2 = Xc[(size_t)q2 * LPR4]; R##3 = Xc[(size_t)q3 * LPR4]; \
    R##4 = Xc[(size_t)q4 * LPR4]; R##5 = Xc[(size_t)q5 * LPR4]; \
    R##6 = Xc[(size_t)q6 * LPR4]; R##7 = Xc[(size_t)q7 * LPR4]; } while (0)
#define ACC8(R) do { ACC4(R##0); ACC4(R##1); ACC4(R##2); ACC4(R##3); \
                     ACC4(R##4); ACC4(R##5); ACC4(R##6); ACC4(R##7); } while (0)
    if (nb > 0) {
        LOAD8(a, p); p += 8;
        int i = 1;
        for (; i + 1 < nb; i += 2) {
            LOAD8(b, p); p += 8;       // issue next 8 gathers
            ACC8(a);                    // consume current (waits only on a)
            LOAD8(a, p); p += 8;
            ACC8(b);
        }
        if (i < nb) { LOAD8(b, p); p += 8; ACC8(a); ACC8(b); }
        else        { ACC8(a); }
    }
#undef LOAD8
#undef ACC8
    for (; p + 2 <= e; p += 2) {
        int ma = (int)csr[p + 0] - n0, mb = (int)csr[p + 1] - n0;
        uint4 u0 = Xc[(size_t)ma * LPR4];
        uint4 u1 = Xc[(size_t)mb * LPR4];
        ACC4(u0); ACC4(u1);
    }
    if (p < e) {
        int ma = (int)csr[p] - n0;
        uint4 u0 = Xc[(size_t)ma * LPR4];
        ACC4(u0);
    }
    unsigned int ow[8];
#pragma unroll
    for (int i = 0; i < 8; ++i)
        ow[i] = (unsigned)f2bf(acc2[i].x) | ((unsigned)f2bf(acc2[i].y) << 16);
    uintx4 o0, o1;
    o0.x = ow[0]; o0.y = ow[1]; o0.z = ow[2]; o0.w = ow[3];
    o1.x = ow[4]; o1.y = ow[5]; o1.z = ow[6]; o1.w = ow[7];
    size_t base = ((size_t)node * LPR4 + chunk) * 2;   // bf16 row = LPR4*2 uintx4
    ((uintx4*)h)[base + 0] = o0;
    ((uintx4*)h)[base + 1] = o1;
}

// ---------------- k1: bucketA || convx(g1) -------------------------------------
__launch_bounds__(256)
__global__ void prep1_kernel(const int* __restrict__ ei1, const int* __restrict__ ei2,
                             unsigned int* __restrict__ stageG, int* __restrict__ gcnt,
                             const float* __restrict__ x1, unsigned char* __restrict__ x8) {
    __shared__ unsigned int shb[8928];
    int b = blockIdx.x;
    if (b < NB) bucketA_body(b, threadIdx.x, ei1, ei2, stageG, gcnt, shb);
    else convx_body((b - NB) * 256 + threadIdx.x, x1, x8);
}

// ---------------- k2: sort(ALL 157 buckets) || convx(g2) -----------------------
__launch_bounds__(256)
__global__ void fused_sortx(const unsigned int* __restrict__ stageG,
                            const int* __restrict__ gcnt,
                            int* __restrict__ row_start,
                            unsigned short* __restrict__ csr,
                            const float* __restrict__ x2,
                            unsigned char* __restrict__ x8g2) {
    __shared__ unsigned int shb[6152];
    int b = blockIdx.x;
    if (b < NB) sort_body(b, threadIdx.x, stageG, gcnt, row_start, csr, shb);
    else convx_body((b - NB) * 256 + threadIdx.x, x2, x8g2);
}

// ---------------- k3: agg1(g1) || 6x convw (small LDS -> full agg residency) ---
__launch_bounds__(256, 4)
__global__ void fused_aggw(const unsigned char* __restrict__ x8,
                           const int* __restrict__ row_start,
                           const unsigned short* __restrict__ csr,
                           unsigned short* __restrict__ h,
                           const float* w11, unsigned short* wt11,
                           const float* w12, unsigned short* wt12,
                           const float* w21, unsigned short* wt21,
                           const float* w22, unsigned short* wt22,
                           const float* w31, unsigned short* wt31,
                           const float* w32, unsigned short* wt32) {
    __shared__ float tile[32 * 33];
    int b = blockIdx.x;
    if (b < AGG256) {
        agg8_body<16, 2>(b, threadIdx.x, x8, row_start, csr, h, 0);
    } else {
        int bl = b - AGG256;
        if (bl < 128)       convw_body(bl,        FIN_D, tile, w11, wt11);
        else if (bl < 384)  convw_body(bl - 128,  HID_D, tile, w12, wt12);
        else if (bl < 640)  convw_body(bl - 384,  HID_D, tile, w21, wt21);
        else if (bl < 896)  convw_body(bl - 640,  HID_D, tile, w22, wt22);
        else if (bl < 1152) convw_body(bl - 896,  HID_D, tile, w31, wt31);
        else                convw_body(bl - 1152, HID_D, tile, w32, wt32);
    }
}

// ---------------- fp8 tile store (epilogue helper, coalesced via LDS) ----------
__device__ __forceinline__ void store_fp8_tile(int row0, int col0, int tid,
                                               unsigned short* smem,
                                               floatx4 acc[4][4], const float* __restrict__ bias,
                                               unsigned char* __restrict__ C8,
                                               int wr, int wc, int lane) {
    unsigned char* tile = (unsigned char*)smem;    // 128*128 = 16KB
    int q = lane >> 4, cn = lane & 15;
#pragma unroll
    for (int j = 0; j < 4; ++j) {
        int lcol = wc * 64 + j * 16 + cn;
        float bv = bias[col0 + lcol];
#pragma unroll
        for (int i = 0; i < 4; ++i) {
            int lrow = wr * 64 + i * 16 + q * 4;
#pragma unroll
            for (int r = 0; r < 4; ++r) {
                float vv = fmaxf(acc[i][j][r] + bv, 0.f);
                int t8 = __builtin_amdgcn_cvt_pk_fp8_f32(vv, 0.f, 0, false);
                tile[(lrow + r) * 128 + lcol] = (unsigned char)(t8 & 0xff);
            }
        }
    }
    __syncthreads();
#pragma unroll
    for (int it = 0; it < 4; ++it) {
        int idx = it * 256 + tid;
        int lrow = idx >> 3, c16 = idx & 7;
        *(uint4*)(C8 + (size_t)(row0 + lrow) * HID_D + col0 + c16 * 16) =
            *(const uint4*)(tile + lrow * 128 + c16 * 16);
    }
}

// ---------------- GEMM epilogue (bf16 path) ------------------------------------
__device__ __forceinline__ void store_bf16(int row0, int col0, int wr, int wc, int lane,
                                           floatx4 acc[4][4], const float* __restrict__ bias,
                                           unsigned short* __restrict__ C) {
    int q = lane >> 4;
    int cn = lane & 15;
#pragma unroll
    for (int j = 0; j < 4; ++j) {
        int col = col0 + wc * 64 + j * 16 + cn;
        float bv = bias[col];
#pragma unroll
        for (int i = 0; i < 4; ++i) {
            int rowb = row0 + wr * 64 + i * 16 + q * 4;
#pragma unroll
            for (int r = 0; r < 4; ++r) {
                float vv = fmaxf(acc[i][j][r] + bv, 0.f);
                C[(size_t)(rowb + r) * HID_D + col] = f2bf(vv);
            }
        }
    }
}

// ---------------- bf16 MFMA GEMM body, BK=32 double-buffered (32KB LDS) --------
// Round-5 known-good body: linear gload_lds staging, syncthreads per K-step.
__device__ __forceinline__ void gemm_body_db(int bx, int by, int tid,
                                             unsigned short* smem,
                                             const unsigned short* __restrict__ A,
                                             const unsigned short* __restrict__ Wt,
                                             const float* __restrict__ bias,
                                             unsigned short* __restrict__ C,
                                             unsigned char* __restrict__ C8, int K) {
    int lane = tid & 63;
    int w = tid >> 6;
    int wr = w >> 1, wc = w & 1;
    int row0 = bx * 128;
    int col0 = by * 128;
    floatx4 acc[4][4] = {};
    int lr = tid >> 2;            // 64 rows per staging pass
    int c8 = (tid & 3) * 8;       // 4 lanes x 8 ushorts = 32-wide row
    const unsigned short* Ag = A + (size_t)row0 * K;
    const unsigned short* Bg = Wt + (size_t)col0 * K;
    int nt = K >> 5;
    {   // prologue: stage tile 0 into buffer 0
        unsigned short* As = smem;
        unsigned short* Bs = smem + 4096;
#pragma unroll
        for (int l = 0; l < 2; ++l) {
            int r = l * 64 + lr;
            __builtin_amdgcn_global_load_lds(
                (const __attribute__((address_space(1))) void*)(Ag + (size_t)r * K + c8),
                (__attribute__((address_space(3))) void*)(As + l * 2048 + tid * 8),
                16, 0, 0);
            __builtin_amdgcn_global_load_lds(
                (const __attribute__((address_space(1))) void*)(Bg + (size_t)r * K + c8),
                (__attribute__((address_space(3))) void*)(Bs + l * 2048 + tid * 8),
                16, 0, 0);
        }
    }
    __syncthreads();
    for (int t = 0; t < nt; ++t) {
        unsigned short* As = smem + ((t & 1) ? 8192 : 0);
        unsigned short* Bs = As + 4096;
        if (t + 1 < nt) {         // issue next-tile loads into the other buffer
            unsigned short* An = smem + ((t & 1) ? 0 : 8192);
            unsigned short* Bn = An + 4096;
            int kt = (t + 1) << 5;
#pragma unroll
            for (int l = 0; l < 2; ++l) {
                int r = l * 64 + lr;
                __builtin_amdgcn_global_load_lds(
                    (const __attribute__((address_space(1))) void*)(Ag + (size_t)r * K + kt + c8),
                    (__attribute__((address_space(3))) void*)(An + l * 2048 + tid * 8),
                    16, 0, 0);
                __builtin_amdgcn_global_load_lds(
                    (const __attribute__((address_space(1))) void*)(Bg + (size_t)r * K + kt + c8),
                    (__attribute__((address_space(3))) void*)(Bn + l * 2048 + tid * 8),
                    16, 0, 0);
            }
        }
        short8 af[4], bf[4];
        int q8 = (lane >> 4) * 8;
#pragma unroll
        for (int i = 0; i < 4; ++i) {
            int m = wr * 64 + i * 16 + (lane & 15);
            af[i] = *(const short8*)&As[m * 32 + q8];
            int n = wc * 64 + i * 16 + (lane & 15);
            bf[i] = *(const short8*)&Bs[n * 32 + q8];
        }
#pragma unroll
        for (int i = 0; i < 4; ++i)
#pragma unroll
            for (int j = 0; j < 4; ++j)
                acc[i][j] = __builtin_amdgcn_mfma_f32_16x16x32_bf16(af[i], bf[j], acc[i][j], 0, 0, 0);
        __syncthreads();          // drains vmcnt: next buffer ready; cur buffer free
    }
    if (C8) {
        store_fp8_tile(row0, col0, tid, smem, acc, bias, C8, wr, wc, lane);
        return;
    }
    store_bf16(row0, col0, wr, wc, lane, acc, bias, C);
}

// ---------------- bf16 MFMA GEMM body, BK=32 TRIPLE-buffered (48KB LDS) --------
// T4 counted-vmcnt: one raw s_barrier per K-step, vmcnt(4) instead of vmcnt(0) —
// next tile's 4 gload_lds stay in flight ACROSS the barrier (m218 mechanism).
// 3 buffers make this race-free: DMA(t+2) targets the slot last read at t-1,
// and barrier(t) guarantees every wave finished iteration t-1. Used only in
// pure-GEMM launches (gemm_pair / fused_gemmlin) to contain the 3-blocks/CU
// LDS occupancy cost.
__device__ __forceinline__ void gemm_body_tb(int bx, int by, int tid,
                                             unsigned short* smem /*24576*/,
                                             const unsigned short* __restrict__ A,
                                             const unsigned short* __restrict__ Wt,
                                             const float* __restrict__ bias,
                                             unsigned short* __restrict__ C,
                                             unsigned char* __restrict__ C8, int K) {
    int lane = tid & 63;
    int w = tid >> 6;
    int wr = w >> 1, wc = w & 1;
    int row0 = bx * 128;
    int col0 = by * 128;
    floatx4 acc[4][4] = {};
    int lr = tid >> 2;
    int c8 = (tid & 3) * 8;
    const unsigned short* Ag = A + (size_t)row0 * K;
    const unsigned short* Bg = Wt + (size_t)col0 * K;
    int nt = K >> 5;
#define STAGE_TB(TI, SLOT) do { \
    unsigned short* As_ = smem + (SLOT) * 8192; \
    unsigned short* Bs_ = As_ + 4096; \
    int kt_ = (TI) << 5; \
    _Pragma("unroll") \
    for (int l = 0; l < 2; ++l) { \
        int r = l * 64 + lr; \
        __builtin_amdgcn_global_load_lds( \
            (const __attribute__((address_space(1))) void*)(Ag + (size_t)r * K + kt_ + c8), \
            (__attribute__((address_space(3))) void*)(As_ + l * 2048 + tid * 8), 16, 0, 0); \
        __builtin_amdgcn_global_load_lds( \
            (const __attribute__((address_space(1))) void*)(Bg + (size_t)r * K + kt_ + c8), \
            (__attribute__((address_space(3))) void*)(Bs_ + l * 2048 + tid * 8), 16, 0, 0); \
    } } while (0)
    STAGE_TB(0, 0);
    if (nt > 1) STAGE_TB(1, 1);
    for (int t = 0; t < nt; ++t) {
        // own tile-t loads complete; tile-t+1's 4 loads stay airborne
        if (t + 1 < nt) { asm volatile("s_waitcnt vmcnt(4)" ::: "memory"); }
        else            { asm volatile("s_waitcnt vmcnt(0)" ::: "memory"); }
        __builtin_amdgcn_sched_barrier(0);
        __builtin_amdgcn_s_barrier();     // all waves: tile-t in LDS, iter t-1 reads done
        __builtin_amdgcn_sched_barrier(0);
        if (t + 2 < nt) STAGE_TB(t + 2, (t + 2) % 3);  // into slot freed at iter t-1
        unsigned short* As = smem + (t % 3) * 8192;
        unsigned short* Bs = As + 4096;
        short8 af[4], bf[4];
        int q8 = (lane >> 4) * 8;
#pragma unroll
        for (int i = 0; i < 4; ++i) {
            int m = wr * 64 + i * 16 + (lane & 15);
            af[i] = *(const short8*)&As[m * 32 + q8];
            int n = wc * 64 + i * 16 + (lane & 15);
            bf[i] = *(const short8*)&Bs[n * 32 + q8];
        }
#pragma unroll
        for (int i = 0; i < 4; ++i)
#pragma unroll
            for (int j = 0; j < 4; ++j)
                acc[i][j] = __builtin_amdgcn_mfma_f32_16x16x32_bf16(af[i], bf[j], acc[i][j], 0, 0, 0);
    }
#undef STAGE_TB
    __syncthreads();   // all waves done reading LDS before epilogue reuses it
    if (C8) {
        store_fp8_tile(row0, col0, tid, smem, acc, bias, C8, wr, wc, lane);
        return;
    }
    store_bf16(row0, col0, wr, wc, lane, acc, bias, C);
}

// two independent gemms (different graphs) in one launch (counted-vmcnt body)
__launch_bounds__(256)
__global__ void gemm_pair(const unsigned short* __restrict__ A1,
                          const unsigned short* __restrict__ W1,
                          const float* __restrict__ b1,
                          unsigned short* __restrict__ C1, unsigned char* C81, int K1,
                          const unsigned short* __restrict__ A2,
                          const unsigned short* __restrict__ W2,
                          const float* __restrict__ b2,
                          unsigned short* __restrict__ C2, unsigned char* C82, int K2) {
    __shared__ unsigned short smem[24576];
    int b = blockIdx.x;
    int bx, by;
    if (b < NGEMM) {
        gmap(b, bx, by);
        gemm_body_tb(bx, by, threadIdx.x, smem, A1, W1, b1, C1, C81, K1);
    } else {
        gmap(b - NGEMM, bx, by);
        gemm_body_tb(bx, by, threadIdx.x, smem, A2, W2, b2, C2, C82, K2);
    }
}

// ---------------- fused: gemm blocks first, fp8-agg blocks after ---------------
template<int LPR4, int NSLAB>
__launch_bounds__(256)
__global__ void fused_k(const unsigned short* __restrict__ A,
                        const unsigned short* __restrict__ Wt,
                        const float* __restrict__ bias,
                        unsigned short* __restrict__ C, unsigned char* C8, int K,
                        const unsigned char* __restrict__ x8,
                        const int* __restrict__ row_start,
                        const unsigned short* __restrict__ csr,
                        unsigned short* __restrict__ h, int n0, int nGemm) {
    __shared__ unsigned short smem[16384];
    int b = blockIdx.x;
    if (b < nGemm) {
        int bx, by;
        gmap(b, bx, by);
        gemm_body_db(bx, by, threadIdx.x, smem, A, Wt, bias, C, C8, K);
    } else {
        agg8_body<LPR4, NSLAB>(b - nGemm, threadIdx.x, x8, row_start, csr, h, n0);
    }
}

// ---------------- final linear [M,512]bf16 @ [512,2]fp32 + b ----------------
__device__ __forceinline__ void lin_body(int bb, int tid, const unsigned short* __restrict__ A,
                                         const float* __restrict__ w, const float* __restrict__ b,
                                         float* __restrict__ o, int M) {
    int wave = tid >> 6;
    int lane = tid & 63;
    int row = bb * 4 + wave;
    if (row >= M) return;
    const uint4* Ar = (const uint4*)(A + (size_t)row * 512);
    uint4 u = Ar[lane];
    float f[8];
    f[0] = bflo(u.x); f[1] = bfhi(u.x); f[2] = bflo(u.y); f[3] = bfhi(u.y);
    f[4] = bflo(u.z); f[5] = bfhi(u.z); f[6] = bflo(u.w); f[7] = bfhi(u.w);
    float s0 = 0.f, s1 = 0.f;
#pragma unroll
    for (int j = 0; j < 8; ++j) {
        int base = (lane * 8 + j) * 2;
        s0 = fmaf(f[j], w[base + 0], s0);
        s1 = fmaf(f[j], w[base + 1], s1);
    }
#pragma unroll
    for (int off = 32; off > 0; off >>= 1) {
        s0 += __shfl_down(s0, off, 64);
        s1 += __shfl_down(s1, off, 64);
    }
    if (lane == 0) { o[row * 2] = s0 + b[0]; o[row * 2 + 1] = s1 + b[1]; }
}

// s10: G32(g2) || lin(g1)  (counted-vmcnt gemm body)
__launch_bounds__(256)
__global__ void fused_gemmlin(const unsigned short* __restrict__ A,
                              const unsigned short* __restrict__ Wt,
                              const float* __restrict__ bias,
                              unsigned short* __restrict__ C, int K,
                              const unsigned short* __restrict__ L,
                              const float* __restrict__ lw, const float* __restrict__ lb,
                              float* __restrict__ o) {
    __shared__ unsigned short smem[24576];
    int b = blockIdx.x;
    if (b < NGEMM) {
        int bx, by;
        gmap(b, bx, by);
        gemm_body_tb(bx, by, threadIdx.x, smem, A, Wt, bias, C, nullptr, K);
    } else {
        lin_body(b - NGEMM, threadIdx.x, L, lw, lb, o, N1);
    }
}

// s11: lin(g2) + dist
__global__ void lin_dist_kernel(const unsigned short* __restrict__ A,
                                const float* __restrict__ w, const float* __restrict__ b,
                                const float* __restrict__ o1,
                                float* __restrict__ o2out,
                                float* __restrict__ dist) {
    int tid = threadIdx.x;
    int wave = tid >> 6;
    int lane = tid & 63;
    int row = blockIdx.x * 4 + wave;
    if (row >= N1) return;
    const uint4* Ar = (const uint4*)(A + (size_t)row * 512);
    uint4 u = Ar[lane];
    float f[8];
    f[0] = bflo(u.x); f[1] = bfhi(u.x); f[2] = bflo(u.y); f[3] = bfhi(u.y);
    f[4] = bflo(u.z); f[5] = bfhi(u.z); f[6] = bflo(u.w); f[7] = bfhi(u.w);
    float s0 = 0.f, s1 = 0.f;
#pragma unroll
    for (int j = 0; j < 8; ++j) {
        int base = (lane * 8 + j) * 2;
        s0 = fmaf(f[j], w[base + 0], s0);
        s1 = fmaf(f[j], w[base + 1], s1);
    }
#pragma unroll
    for (int off = 32; off > 0; off >>= 1) {
        s0 += __shfl_down(s0, off, 64);
        s1 += __shfl_down(s1, off, 64);
    }
    if (lane == 0) {
        float vx = s0 + b[0], vy = s1 + b[1];
        o2out[row * 2] = vx; o2out[row * 2 + 1] = vy;
        float2 a = ((const float2*)o1)[row];
        float d0 = a.x - vx + 1e-6f, d1 = a.y - vy + 1e-6f;
        dist[row] = sqrtf(d0 * d0 + d1 * d1);
    }
}

// LDS-privatized histogram
#define HBLK 20
#define HPB  1000
__launch_bounds__(256)
__global__ void hist_lds_kernel(const float* __restrict__ dist, int* __restrict__ hist) {
    __shared__ int lh[4096];
    int t = threadIdx.x;
    for (int i = t; i < 4096; i += 256) lh[i] = 0;
    __syncthreads();
    int base = blockIdx.x * HPB;
    for (int i = t; i < HPB; i += 256) {
        int idx = base + i;
        if (idx < N1) atomicAdd(&lh[__float_as_uint(dist[idx]) >> 19], 1);
    }
    __syncthreads();
    for (int i = t; i < 4096; i += 256) {
        int v = lh[i];
        if (v) atomicAdd(&hist[i], v);
    }
}

// ---------------- radix-select top-k ----------------
__global__ void selk_kernel(const int* __restrict__ hist, int* __restrict__ selout) {
    __shared__ int tile[256];
    int t = threadIdx.x;
    int running = 0;
    for (int tb = 0; tb < 16; ++tb) {
        int idx = 4095 - (tb * 256 + t);
        int v = hist[idx];
        tile[t] = v;
        __syncthreads();
        for (int off = 1; off < 256; off <<= 1) {
            int x = (t >= off) ? tile[t - off] : 0;
            __syncthreads();
            tile[t] += x;
            __syncthreads();
        }
        int incl = running + tile[t];
        if (incl >= TOPK && incl - v < TOPK) selout[0] = idx;
        running += tile[255];
        __syncthreads();
        if (running >= TOPK) break;
    }
}

__global__ void compact_kernel(const float* __restrict__ dist, const int* __restrict__ selout,
                               int* __restrict__ nc, float* __restrict__ cd, int* __restrict__ ci) {
    int i = blockIdx.x * blockDim.x + threadIdx.x;
    if (i >= N1) return;
    float d = dist[i];
    int b = (int)(__float_as_uint(d) >> 19);
    if (b >= selout[0]) {
        int p = atomicAdd(nc, 1);
        cd[p] = d;
        ci[p] = i;
    }
}

#define CCH 2048
__global__ void rankc_kernel(const float* __restrict__ cd, const int* __restrict__ ci,
                             const int* __restrict__ nc_p, float* __restrict__ vals) {
    __shared__ float ds[CCH];
    __shared__ int   di_[CCH];
    int nc = *nc_p;
    if (blockIdx.x * 256 >= nc) return;
    int t = threadIdx.x;
    int q = blockIdx.x * 256 + t;
    float dq = 0.f; int iq = 0;
    if (q < nc) { dq = cd[q]; iq = ci[q]; }
    int cnt = 0;
    for (int c0 = 0; c0 < nc; c0 += CCH) {
        int lim = min(CCH, nc - c0);
        for (int j = t; j < lim; j += 256) { ds[j] = cd[c0 + j]; di_[j] = ci[c0 + j]; }
        __syncthreads();
        if (q < nc) {
            for (int j = 0; j < lim; ++j) {
                float dj = ds[j];
                cnt += (dj > dq) || (dj == dq && di_[j] < iq);
            }
        }
        __syncthreads();
    }
    if (q < nc && cnt < TOPK) vals[cnt] = dq;
}

// ---------------- head MLP (fc1 split 4-way) ----------------
__launch_bounds__(512)
__global__ void head_kernel(const float* __restrict__ vals,
                            const float* __restrict__ fc1_w, const float* __restrict__ fc1_b,
                            const float* __restrict__ ln1_g, const float* __restrict__ ln1_b,
                            const float* __restrict__ fc2_w, const float* __restrict__ fc2_b,
                            const float* __restrict__ ln2_g, const float* __restrict__ ln2_b,
                            const float* __restrict__ fc3_w, const float* __restrict__ fc3_b,
                            float* __restrict__ out) {
    __shared__ float sv[TOPK];
    __shared__ float a1[128];
    __shared__ float red[512];
    __shared__ float s_m, s_r;
    int t = threadIdx.x;
    for (int i = t; i < TOPK; i += 512) sv[i] = vals[i];
    __syncthreads();
    int g = t >> 7, c = t & 127;
    float part = 0.f;
    for (int j = g * 250; j < g * 250 + 250; ++j)
        part = fmaf(sv[j], fc1_w[j * 128 + c], part);
    red[t] = part;
    __syncthreads();
    float h1 = 0.f;
    if (t < 128) h1 = fc1_b[t] + red[t] + red[t + 128] + red[t + 256] + red[t + 384];
    __syncthreads();
    red[t] = (t < 128) ? h1 : 0.f; __syncthreads();
    for (int s = 256; s > 0; s >>= 1) { if (t < s) red[t] += red[t + s]; __syncthreads(); }
    if (t == 0) s_m = red[0] / 128.f;
    __syncthreads();
    float m1 = s_m;
    float dv = (t < 128) ? (h1 - m1) : 0.f;
    red[t] = dv * dv; __syncthreads();
    for (int s = 256; s > 0; s >>= 1) { if (t < s) red[t] += red[t + s]; __syncthreads(); }
    if (t == 0) s_r = rsqrtf(red[0] / 128.f + 1e-5f);
    __syncthreads();
    float r1 = s_r;
    if (t < 128) a1[t] = fmaxf((h1 - m1) * r1 * ln1_g[t] + ln1_b[t], 0.f);
    __syncthreads();
    float h2 = fc2_b[t];
    for (int j = 0; j < 128; ++j) h2 = fmaf(a1[j], fc2_w[j * 512 + t], h2);
    red[t] = h2; __syncthreads();
    for (int s = 256; s > 0; s >>= 1) { if (t < s) red[t] += red[t + s]; __syncthreads(); }
    if (t == 0) s_m = red[0] / 512.f;
    __syncthreads();
    float m2 = s_m;
    float d2 = h2 - m2;
    red[t] = d2 * d2; __syncthreads();
    for (int s = 256; s > 0; s >>= 1) { if (t < s) red[t] += red[t + s]; __syncthreads(); }
    if (t == 0) s_r = rsqrtf(red[0] / 512.f + 1e-5f);
    __syncthreads();
    float r2 = s_r;
    float y2 = fmaxf((h2 - m2) * r2 * ln2_g[t] + ln2_b[t], 0.f);
    red[t] = y2 * fc3_w[t]; __syncthreads();
    for (int s = 256; s > 0; s >>= 1) { if (t < s) red[t] += red[t + s]; __syncthreads(); }
    if (t == 0) out[0] = 1.f / (1.f + expf(-(red[0] + fc3_b[0])));
}

extern "C" void kernel_launch(void* const* d_in, const int* in_sizes, int n_in,
                              void* d_out, int out_size, void* d_ws, size_t ws_size,
                              hipStream_t stream) {
    const float* x1   = (const float*)d_in[0];
    const int*   ei1  = (const int*)d_in[1];
    const float* x2   = (const float*)d_in[2];
    const int*   ei2  = (const int*)d_in[3];
    const float* w11  = (const float*)d_in[4];
    const float* b11  = (const float*)d_in[5];
    const float* w12  = (const float*)d_in[6];
    const float* b12  = (const float*)d_in[7];
    const float* w21  = (const float*)d_in[8];
    const float* b21  = (const float*)d_in[9];
    const float* w22  = (const float*)d_in[10];
    const float* b22  = (const float*)d_in[11];
    const float* w31  = (const float*)d_in[12];
    const float* b31  = (const float*)d_in[13];
    const float* w32  = (const float*)d_in[14];
    const float* b32  = (const float*)d_in[15];
    const float* lw   = (const float*)d_in[16];
    const float* lb   = (const float*)d_in[17];
    const float* fc1w = (const float*)d_in[18];
    const float* fc1b = (const float*)d_in[19];
    const float* ln1g = (const float*)d_in[20];
    const float* ln1b = (const float*)d_in[21];
    const float* fc2w = (const float*)d_in[22];
    const float* fc2b = (const float*)d_in[23];
    const float* ln2g = (const float*)d_in[24];
    const float* ln2b = (const float*)d_in[25];
    const float* fc3w = (const float*)d_in[26];
    const float* fc3b = (const float*)d_in[27];

    char* ws = (char*)d_ws;
    size_t off = 0;
    auto alloc = [&](size_t bytes) -> void* {
        void* p = ws + off;
        off += (bytes + 255) & ~(size_t)255;
        return p;
    };
    unsigned char*  XB8 = (unsigned char*)alloc((size_t)NT * FIN_D);       // fp8 inputs
    unsigned short* H0a = (unsigned short*)alloc((size_t)MP1 * HID_D * 2);
    unsigned short* H1a = (unsigned short*)alloc((size_t)MP1 * HID_D * 2);
    unsigned short* H0b = (unsigned short*)alloc((size_t)MP1 * HID_D * 2);
    unsigned short* H1b = (unsigned short*)alloc((size_t)MP1 * HID_D * 2);
    unsigned char*  F8a = (unsigned char*)alloc((size_t)MP1 * HID_D);      // fp8 agg tables
    unsigned char*  F8b = (unsigned char*)alloc((size_t)MP1 * HID_D);
    unsigned short* wt11 = (unsigned short*)alloc((size_t)HID_D * FIN_D * 2);
    unsigned short* wt12 = (unsigned short*)alloc((size_t)HID_D * HID_D * 2);
    unsigned short* wt21 = (unsigned short*)alloc((size_t)HID_D * HID_D * 2);
    unsigned short* wt22 = (unsigned short*)alloc((size_t)HID_D * HID_D * 2);
    unsigned short* wt31 = (unsigned short*)alloc((size_t)HID_D * HID_D * 2);
    unsigned short* wt32 = (unsigned short*)alloc((size_t)HID_D * HID_D * 2);
    float* o         = (float*)alloc((size_t)NT * 2 * 4);
    float* dist      = (float*)alloc((size_t)N1 * 4);
    float* vals      = (float*)alloc((size_t)TOPK * 4);
    int*   row_start = (int*)alloc((size_t)(NT + 1) * 4);
    unsigned short* csr16 = (unsigned short*)alloc((size_t)ET * 2);
    unsigned int* stageG  = (unsigned int*)alloc((size_t)NB * CAP * 4);    // 6.4MB bucket staging
    int*   gcnt      = (int*)alloc((size_t)160 * 4);
    int*   selblk    = (int*)alloc((size_t)(4096 + 64) * 4);
    int*   hist      = selblk;
    int*   nc        = selblk + 4096;
    int*   selout    = (int*)alloc(2 * 4);
    float* cd        = (float*)alloc((size_t)N1 * 4);
    int*   ci        = (int*)alloc((size_t)N1 * 4);

    const unsigned char* XB8g2 = XB8 + (size_t)N1 * FIN_D;

    // ---- pipelined prep: nothing latency-bound runs naked ----
    hipMemsetAsync(gcnt, 0, 160 * sizeof(int), stream);
    hipMemsetAsync(selblk, 0, (4096 + 64) * sizeof(int), stream);
    // k1: bucketA || convx(g1)
    prep1_kernel<<<NB + 5000, 256, 0, stream>>>(ei1, ei2, stageG, gcnt, x1, XB8);
    // k2: sort(all buckets) || convx(g2)
    fused_sortx<<<NB + 5000, 256, 0, stream>>>(stageG, gcnt, row_start, csr16,
                                               x2, (unsigned char*)XB8g2);
    // k3: agg1(g1) || 6x convw  (4.2KB LDS -> full agg residency)
    fused_aggw<<<AGG256 + 1408, 256, 0, stream>>>(
        XB8, row_start, csr16, H0a,
        w11, wt11, w12, wt12, w21, wt21, w22, wt22, w31, wt31, w32, wt32);

    // ---- staggered two-graph pipeline ----
    // s2: G11(g1) bf16 || agg1(g2) fp8
    fused_k<16, 2><<<NGEMM + AGG256, 256, 0, stream>>>(H0a, wt11, b11, H1a, nullptr, FIN_D,
                                                       XB8g2, row_start, csr16, H0b, N1, NGEMM);
    // s3: G12(g1)->fp8 F8a + G11(g2)->bf16 H1b
    gemm_pair<<<2 * NGEMM, 256, 0, stream>>>(H1a, wt12, b12, nullptr, F8a, HID_D,
                                             H0b, wt11, b11, H1b, nullptr, FIN_D);
    // s4: G12(g2)->fp8 F8b || agg2(g1): F8a -> H1a
    fused_k<32, 4><<<NGEMM + AGG512, 256, 0, stream>>>(H1b, wt12, b12, nullptr, F8b, HID_D,
                                                       F8a, row_start, csr16, H1a, 0, NGEMM);
    // s5: G21(g1): H1a -> H0a || agg2(g2): F8b -> H1b
    fused_k<32, 4><<<NGEMM + AGG512, 256, 0, stream>>>(H1a, wt21, b21, H0a, nullptr, HID_D,
                                                       F8b, row_start, csr16, H1b, N1, NGEMM);
    // s6: G22(g1)->fp8 F8a + G21(g2): H1b -> H0b
    gemm_pair<<<2 * NGEMM, 256, 0, stream>>>(H0a, wt22, b22, nullptr, F8a, HID_D,
                                             H1b, wt21, b21, H0b, nullptr, HID_D);
    // s7: G22(g2)->fp8 F8b || agg3(g1): F8a -> H1a
    fused_k<32, 4><<<NGEMM + AGG512, 256, 0, stream>>>(H0b, wt22, b22, nullptr, F8b, HID_D,
                                                       F8a, row_start, csr16, H1a, 0, NGEMM);
    // s8: G31(g1): H1a -> H0a || agg3(g2): F8b -> H1b
    fused_k<32, 4><<<NGEMM + AGG512, 256, 0, stream>>>(H1a, wt31, b31, H0a, nullptr, HID_D,
                                                       F8b, row_start, csr16, H1b, N1, NGEMM);
    // s9: G32(g1): H0a -> H1a + G31(g2): H1b -> H0b
    gemm_pair<<<2 * NGEMM, 256, 0, stream>>>(H0a, wt32, b32, H1a, nullptr, HID_D,
                                             H1b, wt31, b31, H0b, nullptr, HID_D);
    // s10: G32(g2): H0b -> H1b || lin(g1) reads H1a
    fused_gemmlin<<<NGEMM + (N1 + 3) / 4, 256, 0, stream>>>(H0b, wt32, b32, H1b, HID_D,
                                                            H1a, lw, lb, o);
    // s11: lin(g2) + dist
    lin_dist_kernel<<<(N1 + 3) / 4, 256, 0, stream>>>(H1b, lw, lb, o,
                                                      o + 2 * (size_t)N1, dist);
    // s12: LDS-privatized histogram
    hist_lds_kernel<<<HBLK, 256, 0, stream>>>(dist, hist);

    // ---- radix-select top-k + head ----
    selk_kernel<<<1, 256, 0, stream>>>(hist, selout);
    compact_kernel<<<(N1 + 255) / 256, 256, 0, stream>>>(dist, selout, nc, cd, ci);
    rankc_kernel<<<(N1 + 255) / 256, 256, 0, stream>>>(cd, ci, nc, vals);
    head_kernel<<<1, 512, 0, stream>>>(vals, fc1w, fc1b, ln1g, ln1b,
                                       fc2w, fc2b, ln2g, ln2b, fc3w, fc3b,
                                       (float*)d_out);
}

// Round 9
// 662.559 us; speedup vs baseline: 1.1495x; 1.0319x over previous
//
#include <hip/hip_runtime.h>
#include <hip/hip_bf16.h>
#include <math.h>

#define N1      20000          // nodes per graph
#define NT      40000          // both graphs
#define E1      640000         // edges per graph
#define ET      1280000
#define FIN_D   256
#define HID_D   512
#define TOPK    1000
#define MP1     20096          // 157 * 128 (padded M per graph)
#define NGEMM   628            // 157 x 4 blocks per 20096x512 gemm
#define AGG256  1250           // 2 slabs * 625 groups (32 nodes/group, 128B/group-slab)
#define AGG512  2500           // 4 slabs * 625 groups

// bucketed CSR build: 157 buckets x 256 nodes, line-granular writes only
#define NB       157           // ceil(40000/256)
#define CAP      10240         // per-bucket staging capacity (mean 8153, sigma ~90)
#define BK_CHUNK 8192          // edges per bucketA block

typedef __attribute__((ext_vector_type(8))) short short8;
typedef __attribute__((ext_vector_type(4))) float floatx4;
typedef __attribute__((ext_vector_type(2))) float floatx2;
typedef unsigned int uintx4 __attribute__((ext_vector_type(4)));

__device__ __forceinline__ unsigned short f2bf(float f) {
    union { __hip_bfloat16 h; unsigned short u; } cv;
    cv.h = __float2bfloat16(f);
    return cv.u;
}
__device__ __forceinline__ float bflo(unsigned int u) {
    union { unsigned int i; float f; } c; c.i = u << 16; return c.f;
}
__device__ __forceinline__ float bfhi(unsigned int u) {
    union { unsigned int i; float f; } c; c.i = u & 0xffff0000u; return c.f;
}

// XCD-aligned GEMM block map: the 4 gemm ids sharing an A-panel are 8 apart ->
// same XCD residue under round-robin dispatch -> A panel fetched once per XCD.
__device__ __forceinline__ void gmap(int b, int& bx, int& by) {
    const int nfull = (157 / 8) * 32;      // 608
    if (b < nfull) {
        int chunk = b >> 5, w = b & 31;
        bx = (chunk << 3) + (w & 7);
        by = w >> 3;
    } else {
        int i = b - nfull;                 // 20 tail blocks: panels 152..156
        bx = 152 + i % 5;
        by = i / 5;
    }
}

// ---------------- prep bodies: convw / convx ----------------
__device__ __forceinline__ void convw_body(int bl, int K, float* tile /*32x33*/,
                                           const float* __restrict__ W,
                                           unsigned short* __restrict__ Wt) {
    int kb = K / 32;
    int k0 = (bl % kb) * 32, n0 = (bl / kb) * 32;
    int tx = threadIdx.x & 31, ty = threadIdx.x >> 5;
    for (int r = ty; r < 32; r += 8) tile[r * 33 + tx] = W[(size_t)(k0 + r) * HID_D + n0 + tx];
    __syncthreads();
    for (int r = ty; r < 32; r += 8)
        Wt[(size_t)(n0 + r) * K + k0 + tx] = f2bf(tile[tx * 33 + r]);
}
__device__ __forceinline__ void convx_body(int i, const float* __restrict__ x,
                                           unsigned char* __restrict__ x8) {
    float4 f = ((const float4*)x)[i];
    int p = __builtin_amdgcn_cvt_pk_fp8_f32(f.x, f.y, 0, false);
    p = __builtin_amdgcn_cvt_pk_fp8_f32(f.z, f.w, p, true);
    ((unsigned int*)x8)[i] = (unsigned int)p;
}

// ---------------- bucketA: LDS-staged bucket scatter ---------------------------
__device__ __forceinline__ void bucketA_body(int bb, int t,
                                             const int* __restrict__ ei1,
                                             const int* __restrict__ ei2,
                                             unsigned int* __restrict__ stageG,
                                             int* __restrict__ gcnt,
                                             unsigned int* shb) {
    unsigned int* stg   = shb;           // 8192 staged entries
    unsigned int* scn   = shb + 8192;    // 256 scan scratch
    unsigned int* hoff  = shb + 8448;    // 160 exclusive offsets
    unsigned int* hcur  = shb + 8608;    // 160 hist then cursor
    unsigned int* hbase = shb + 8768;    // 160 reserved global bases
    int e0 = bb * BK_CHUNK;
    int total = ET - e0; if (total > BK_CHUNK) total = BK_CHUNK;
    for (int i = t; i < 160; i += 256) hcur[i] = 0;
    __syncthreads();
    for (int k = 0; k < 32; ++k) {                 // pass 1: hist over dst buckets
        int e = e0 + k * 256 + t;
        if (e < ET) {
            int d = (e < E1) ? ei1[E1 + e] : (ei2[E1 + (e - E1)] + N1);
            atomicAdd(&hcur[d >> 8], 1u);
        }
    }
    __syncthreads();
    unsigned int v = (t < NB) ? hcur[t] : 0u;
    scn[t] = v; __syncthreads();
    for (int off = 1; off < 256; off <<= 1) {
        unsigned int x = (t >= off) ? scn[t - off] : 0u;
        __syncthreads(); scn[t] += x; __syncthreads();
    }
    if (t < NB) {
        unsigned int ex = scn[t] - v;
        hoff[t] = ex;
        hbase[t] = (unsigned int)atomicAdd(&gcnt[t], (int)v);
    }
    __syncthreads();
    if (t < NB) hcur[t] = hoff[t];
    __syncthreads();
    for (int k = 0; k < 32; ++k) {                 // pass 2: place into LDS by bucket
        int e = e0 + k * 256 + t;
        if (e < ET) {
            int s, d;
            if (e < E1) { s = ei1[e]; d = ei1[E1 + e]; }
            else        { int ee = e - E1; s = ei2[ee] + N1; d = ei2[E1 + ee] + N1; }
            unsigned int b8 = (unsigned int)(d >> 8);
            unsigned int pos = atomicAdd(&hcur[b8], 1u);
            stg[pos] = (unsigned int)s | ((unsigned int)(d & 255) << 16) | (b8 << 24);
        }
    }
    __syncthreads();
    for (int i = t; i < total; i += 256) {         // flush: contiguous per-bucket runs
        unsigned int e = stg[i];
        unsigned int b8 = e >> 24;
        unsigned int g = hbase[b8] + ((unsigned int)i - hoff[b8]);
        if (g < CAP) stageG[(size_t)b8 * CAP + g] = e;
    }
}

// ---------------- per-bucket counting sort body -> row_start + csr (ushort) ----
__device__ __forceinline__ void sort_body(int b, int t,
                                          const unsigned int* __restrict__ stageG,
                                          const int* __restrict__ gcnt,
                                          int* __restrict__ row_start,
                                          unsigned short* __restrict__ csr,
                                          unsigned int* shb) {
    unsigned int* cnts = shb;
    unsigned int* offs = shb + 256;
    unsigned int* cur  = shb + 512;
    unsigned int* scn  = shb + 768;
    unsigned short* outb = (unsigned short*)(shb + 1024);   // CAP ushorts = 5120 uints
    int* s_base = (int*)(shb + 6144);
    unsigned int gv = (t < NB) ? (unsigned int)gcnt[t] : 0u;
    scn[t] = gv; __syncthreads();
    for (int off = 1; off < 256; off <<= 1) {
        unsigned int x = (t >= off) ? scn[t - off] : 0u;
        __syncthreads(); scn[t] += x; __syncthreads();
    }
    if (t == b) s_base[0] = (int)(scn[t] - gv);
    cnts[t] = 0;
    __syncthreads();
    int base = s_base[0];
    int cnt = gcnt[b]; if (cnt > CAP) cnt = CAP;
    const unsigned int* src = stageG + (size_t)b * CAP;
    for (int i = t; i < cnt; i += 256) atomicAdd(&cnts[(src[i] >> 16) & 255], 1u);
    __syncthreads();
    unsigned int v = cnts[t];
    offs[t] = v; __syncthreads();
    for (int off = 1; off < 256; off <<= 1) {
        unsigned int x = (t >= off) ? offs[t - off] : 0u;
        __syncthreads(); offs[t] += x; __syncthreads();
    }
    unsigned int excl = offs[t] - v;
    cur[t] = excl;
    int node = b * 256 + t;
    if (node < NT) row_start[node] = base + (int)excl;
    if (b == 0 && t == 0) row_start[NT] = ET;
    __syncthreads();
    for (int i = t; i < cnt; i += 256) {
        unsigned int e = src[i];
        unsigned int p = atomicAdd(&cur[(e >> 16) & 255], 1u);
        outb[p] = (unsigned short)(e & 0xffffu);
    }
    __syncthreads();
    for (int i = t; i < cnt; i += 256) csr[base + i] = outb[i];
}

// ---------------- fp8 GIN aggregation body (uint4 gathers, 2-deep pipeline) ----
#define ACC4(u) do { \
    acc2[0] += __builtin_amdgcn_cvt_pk_f32_fp8((int)(u).x, false); \
    acc2[1] += __builtin_amdgcn_cvt_pk_f32_fp8((int)(u).x, true);  \
    acc2[2] += __builtin_amdgcn_cvt_pk_f32_fp8((int)(u).y, false); \
    acc2[3] += __builtin_amdgcn_cvt_pk_f32_fp8((int)(u).y, true);  \
    acc2[4] += __builtin_amdgcn_cvt_pk_f32_fp8((int)(u).z, false); \
    acc2[5] += __builtin_amdgcn_cvt_pk_f32_fp8((int)(u).z, true);  \
    acc2[6] += __builtin_amdgcn_cvt_pk_f32_fp8((int)(u).w, false); \
    acc2[7] += __builtin_amdgcn_cvt_pk_f32_fp8((int)(u).w, true);  } while (0)

template<int LPR4, int NSLAB>   // LPR4 = uint4 per fp8 row (D/16); NSLAB = D/128
__device__ __forceinline__ void agg8_body(int ab, int tid,
                                          const unsigned char* __restrict__ x8,
                                          const int* __restrict__ row_start,
                                          const unsigned short* __restrict__ csr,
                                          unsigned short* __restrict__ h, int n0) {
    int slab = ab & (NSLAB - 1);               // XCD-pinned (blockIdx round-robin)
    int grp  = ab / NSLAB;                     // 0..624
    int node = grp * 32 + (tid >> 3);          // exact: 625*32 = 20000
    int lanec = tid & 7;
    int chunk = slab * 8 + lanec;              // uint4 index within fp8 row
    const uint4* Xc = (const uint4*)x8 + chunk;
    floatx2 acc2[8] = {};
    uint4 v = Xc[(size_t)node * LPR4];
    ACC4(v);                                   // self term (fp8)
    int nid = n0 + node;
    int s = row_start[nid], e = row_start[nid + 1];
    int p = s;
    int nb = (e - s) >> 3;
    uint4 a0, a1, a2, a3, a4, a5, a6, a7;
    uint4 b0, b1, b2, b3, b4, b5, b6, b7;
#define LOAD8(R, P) do { \
    int q0 = (int)csr[(P) + 0] - n0, q1 = (int)csr[(P) + 1] - n0; \
    int q2 = (int)csr[(P) + 2] - n0, q3 = (int)csr[(P) + 3] - n0; \
    int q4 = (int)csr[(P) + 4] - n0, q5 = (int)csr[(P) + 5] - n0; \
    int q6 = (int)csr[(P) + 6] - n0, q7 = (int)csr[(P) + 7] - n0; \
    R##0 = Xc[(size_t)q0 * LPR4]; R##1 = Xc[(size_t)q1 * LPR4]; \
    R##2 = Xc[(size_t)q2 * LPR4]; R##3 = Xc[(size_t)q3 * LPR4]; \
    R##4 = Xc[(size_t)q4 * LPR4]; R##5 = Xc[(size_t)q5 * LPR4]; \
    R##6 = Xc[(size_t)q6 * LPR4]; R##7 = Xc[(size_t)q7 * LPR4]; } while (0)
#define ACC8(R) do { ACC4(R##0); ACC4(R##1); ACC4(R##2); ACC4(R##3); \
                     ACC4(R##4); ACC4(R##5); ACC4(R##6); ACC4(R##7); } while (0)
    if (nb > 0) {
        LOAD8(a, p); p += 8;
        int i = 1;
        for (; i + 1 < nb; i += 2) {
            LOAD8(b, p); p += 8;       // issue next 8 gathers
            ACC8(a);                    // consume current (waits only on a)
            LOAD8(a, p); p += 8;
            ACC8(b);
        }
        if (i < nb) { LOAD8(b, p); p += 8; ACC8(a); ACC8(b); }
        else        { ACC8(a); }
    }
#undef LOAD8
#undef ACC8
    for (; p + 2 <= e; p += 2) {
        int ma = (int)csr[p + 0] - n0, mb = (int)csr[p + 1] - n0;
        uint4 u0 = Xc[(size_t)ma * LPR4];
        uint4 u1 = Xc[(size_t)mb * LPR4];
        ACC4(u0); ACC4(u1);
    }
    if (p < e) {
        int ma = (int)csr[p] - n0;
        uint4 u0 = Xc[(size_t)ma * LPR4];
        ACC4(u0);
    }
    unsigned int ow[8];
#pragma unroll
    for (int i = 0; i < 8; ++i)
        ow[i] = (unsigned)f2bf(acc2[i].x) | ((unsigned)f2bf(acc2[i].y) << 16);
    uintx4 o0, o1;
    o0.x = ow[0]; o0.y = ow[1]; o0.z = ow[2]; o0.w = ow[3];
    o1.x = ow[4]; o1.y = ow[5]; o1.z = ow[6]; o1.w = ow[7];
    size_t base = ((size_t)node * LPR4 + chunk) * 2;   // bf16 row = LPR4*2 uintx4
    ((uintx4*)h)[base + 0] = o0;
    ((uintx4*)h)[base + 1] = o1;
}

// ---------------- k1: bucketA || convx(g1) -------------------------------------
__launch_bounds__(256)
__global__ void prep1_kernel(const int* __restrict__ ei1, const int* __restrict__ ei2,
                             unsigned int* __restrict__ stageG, int* __restrict__ gcnt,
                             const float* __restrict__ x1, unsigned char* __restrict__ x8) {
    __shared__ unsigned int shb[8928];
    int b = blockIdx.x;
    if (b < NB) bucketA_body(b, threadIdx.x, ei1, ei2, stageG, gcnt, shb);
    else convx_body((b - NB) * 256 + threadIdx.x, x1, x8);
}

// ---------------- k2: sort(ALL 157 buckets) || convx(g2) -----------------------
__launch_bounds__(256)
__global__ void fused_sortx(const unsigned int* __restrict__ stageG,
                            const int* __restrict__ gcnt,
                            int* __restrict__ row_start,
                            unsigned short* __restrict__ csr,
                            const float* __restrict__ x2,
                            unsigned char* __restrict__ x8g2) {
    __shared__ unsigned int shb[6152];
    int b = blockIdx.x;
    if (b < NB) sort_body(b, threadIdx.x, stageG, gcnt, row_start, csr, shb);
    else convx_body((b - NB) * 256 + threadIdx.x, x2, x8g2);
}

// ---------------- k3: agg1(g1) || 6x convw (small LDS -> full agg residency) ---
__launch_bounds__(256, 4)
__global__ void fused_aggw(const unsigned char* __restrict__ x8,
                           const int* __restrict__ row_start,
                           const unsigned short* __restrict__ csr,
                           unsigned short* __restrict__ h,
                           const float* w11, unsigned short* wt11,
                           const float* w12, unsigned short* wt12,
                           const float* w21, unsigned short* wt21,
                           const float* w22, unsigned short* wt22,
                           const float* w31, unsigned short* wt31,
                           const float* w32, unsigned short* wt32) {
    __shared__ float tile[32 * 33];
    int b = blockIdx.x;
    if (b < AGG256) {
        agg8_body<16, 2>(b, threadIdx.x, x8, row_start, csr, h, 0);
    } else {
        int bl = b - AGG256;
        if (bl < 128)       convw_body(bl,        FIN_D, tile, w11, wt11);
        else if (bl < 384)  convw_body(bl - 128,  HID_D, tile, w12, wt12);
        else if (bl < 640)  convw_body(bl - 384,  HID_D, tile, w21, wt21);
        else if (bl < 896)  convw_body(bl - 640,  HID_D, tile, w22, wt22);
        else if (bl < 1152) convw_body(bl - 896,  HID_D, tile, w31, wt31);
        else                convw_body(bl - 1152, HID_D, tile, w32, wt32);
    }
}

// ---------------- fp8 tile store (epilogue helper, coalesced via LDS) ----------
// Shared between bodies exactly as in round 5 (fused_k measured 59us with this).
__device__ __forceinline__ void store_fp8_tile(int row0, int col0, int tid,
                                               unsigned short* smem,
                                               floatx4 acc[4][4], const float* __restrict__ bias,
                                               unsigned char* __restrict__ C8,
                                               int wr, int wc, int lane) {
    unsigned char* tile = (unsigned char*)smem;    // 128*128 = 16KB
    int q = lane >> 4, cn = lane & 15;
#pragma unroll
    for (int j = 0; j < 4; ++j) {
        int lcol = wc * 64 + j * 16 + cn;
        float bv = bias[col0 + lcol];
#pragma unroll
        for (int i = 0; i < 4; ++i) {
            int lrow = wr * 64 + i * 16 + q * 4;
#pragma unroll
            for (int r = 0; r < 4; ++r) {
                float vv = fmaxf(acc[i][j][r] + bv, 0.f);
                int t8 = __builtin_amdgcn_cvt_pk_fp8_f32(vv, 0.f, 0, false);
                tile[(lrow + r) * 128 + lcol] = (unsigned char)(t8 & 0xff);
            }
        }
    }
    __syncthreads();
#pragma unroll
    for (int it = 0; it < 4; ++it) {
        int idx = it * 256 + tid;
        int lrow = idx >> 3, c16 = idx & 7;
        *(uint4*)(C8 + (size_t)(row0 + lrow) * HID_D + col0 + c16 * 16) =
            *(const uint4*)(tile + lrow * 128 + c16 * 16);
    }
}

// ---------------- bf16 MFMA GEMM body, BK=32 double-buffered (32KB LDS) --------
// EXACT round-5 body (inline bf16 epilogue — r8's shared store_bf16 helper
// perturbed this body's LDS scheduling: conflicts +25%, fused_k 59->69us).
__device__ __forceinline__ void gemm_body_db(int bx, int by, int tid,
                                             unsigned short* smem,
                                             const unsigned short* __restrict__ A,
                                             const unsigned short* __restrict__ Wt,
                                             const float* __restrict__ bias,
                                             unsigned short* __restrict__ C,
                                             unsigned char* __restrict__ C8, int K) {
    const int N = HID_D;
    int lane = tid & 63;
    int w = tid >> 6;
    int wr = w >> 1, wc = w & 1;
    int row0 = bx * 128;
    int col0 = by * 128;
    floatx4 acc[4][4] = {};
    int lr = tid >> 2;            // 64 rows per staging pass
    int c8 = (tid & 3) * 8;       // 4 lanes x 8 ushorts = 32-wide row
    const unsigned short* Ag = A + (size_t)row0 * K;
    const unsigned short* Bg = Wt + (size_t)col0 * K;
    int nt = K >> 5;
    {   // prologue: stage tile 0 into buffer 0
        unsigned short* As = smem;
        unsigned short* Bs = smem + 4096;
#pragma unroll
        for (int l = 0; l < 2; ++l) {
            int r = l * 64 + lr;
            __builtin_amdgcn_global_load_lds(
                (const __attribute__((address_space(1))) void*)(Ag + (size_t)r * K + c8),
                (__attribute__((address_space(3))) void*)(As + l * 2048 + tid * 8),
                16, 0, 0);
            __builtin_amdgcn_global_load_lds(
                (const __attribute__((address_space(1))) void*)(Bg + (size_t)r * K + c8),
                (__attribute__((address_space(3))) void*)(Bs + l * 2048 + tid * 8),
                16, 0, 0);
        }
    }
    __syncthreads();
    for (int t = 0; t < nt; ++t) {
        unsigned short* As = smem + ((t & 1) ? 8192 : 0);
        unsigned short* Bs = As + 4096;
        if (t + 1 < nt) {         // issue next-tile loads into the other buffer
            unsigned short* An = smem + ((t & 1) ? 0 : 8192);
            unsigned short* Bn = An + 4096;
            int kt = (t + 1) << 5;
#pragma unroll
            for (int l = 0; l < 2; ++l) {
                int r = l * 64 + lr;
                __builtin_amdgcn_global_load_lds(
                    (const __attribute__((address_space(1))) void*)(Ag + (size_t)r * K + kt + c8),
                    (__attribute__((address_space(3))) void*)(An + l * 2048 + tid * 8),
                    16, 0, 0);
                __builtin_amdgcn_global_load_lds(
                    (const __attribute__((address_space(1))) void*)(Bg + (size_t)r * K + kt + c8),
                    (__attribute__((address_space(3))) void*)(Bn + l * 2048 + tid * 8),
                    16, 0, 0);
            }
        }
        short8 af[4], bf[4];
        int q8 = (lane >> 4) * 8;
#pragma unroll
        for (int i = 0; i < 4; ++i) {
            int m = wr * 64 + i * 16 + (lane & 15);
            af[i] = *(const short8*)&As[m * 32 + q8];
            int n = wc * 64 + i * 16 + (lane & 15);
            bf[i] = *(const short8*)&Bs[n * 32 + q8];
        }
#pragma unroll
        for (int i = 0; i < 4; ++i)
#pragma unroll
            for (int j = 0; j < 4; ++j)
                acc[i][j] = __builtin_amdgcn_mfma_f32_16x16x32_bf16(af[i], bf[j], acc[i][j], 0, 0, 0);
        __syncthreads();          // drains vmcnt: next buffer ready; cur buffer free
    }
    if (C8) {
        store_fp8_tile(row0, col0, tid, smem, acc, bias, C8, wr, wc, lane);
        return;
    }
    int q = lane >> 4;
    int cn = lane & 15;
#pragma unroll
    for (int j = 0; j < 4; ++j) {
        int col = col0 + wc * 64 + j * 16 + cn;
        float bv = bias[col];
#pragma unroll
        for (int i = 0; i < 4; ++i) {
            int rowb = row0 + wr * 64 + i * 16 + q * 4;
#pragma unroll
            for (int r = 0; r < 4; ++r) {
                float vv = fmaxf(acc[i][j][r] + bv, 0.f);
                C[(size_t)(rowb + r) * N + col] = f2bf(vv);
            }
        }
    }
}

// ---------------- bf16 MFMA GEMM body, BK=32 TRIPLE-buffered (48KB LDS) --------
// T4 counted-vmcnt: one raw s_barrier per K-step, vmcnt(4) instead of vmcnt(0) —
// next tile's 4 gload_lds stay in flight ACROSS the barrier (m218 mechanism).
// 3 buffers make this race-free. Own inline bf16 epilogue (no shared helper).
__device__ __forceinline__ void gemm_body_tb(int bx, int by, int tid,
                                             unsigned short* smem /*24576*/,
                                             const unsigned short* __restrict__ A,
                                             const unsigned short* __restrict__ Wt,
                                             const float* __restrict__ bias,
                                             unsigned short* __restrict__ C,
                                             unsigned char* __restrict__ C8, int K) {
    int lane = tid & 63;
    int w = tid >> 6;
    int wr = w >> 1, wc = w & 1;
    int row0 = bx * 128;
    int col0 = by * 128;
    floatx4 acc[4][4] = {};
    int lr = tid >> 2;
    int c8 = (tid & 3) * 8;
    const unsigned short* Ag = A + (size_t)row0 * K;
    const unsigned short* Bg = Wt + (size_t)col0 * K;
    int nt = K >> 5;
#define STAGE_TB(TI, SLOT) do { \
    unsigned short* As_ = smem + (SLOT) * 8192; \
    unsigned short* Bs_ = As_ + 4096; \
    int kt_ = (TI) << 5; \
    _Pragma("unroll") \
    for (int l = 0; l < 2; ++l) { \
        int r = l * 64 + lr; \
        __builtin_amdgcn_global_load_lds( \
            (const __attribute__((address_space(1))) void*)(Ag + (size_t)r * K + kt_ + c8), \
            (__attribute__((address_space(3))) void*)(As_ + l * 2048 + tid * 8), 16, 0, 0); \
        __builtin_amdgcn_global_load_lds( \
            (const __attribute__((address_space(1))) void*)(Bg + (size_t)r * K + kt_ + c8), \
            (__attribute__((address_space(3))) void*)(Bs_ + l * 2048 + tid * 8), 16, 0, 0); \
    } } while (0)
    STAGE_TB(0, 0);
    if (nt > 1) STAGE_TB(1, 1);
    for (int t = 0; t < nt; ++t) {
        // own tile-t loads complete; tile-t+1's 4 loads stay airborne
        if (t + 1 < nt) { asm volatile("s_waitcnt vmcnt(4)" ::: "memory"); }
        else            { asm volatile("s_waitcnt vmcnt(0)" ::: "memory"); }
        __builtin_amdgcn_sched_barrier(0);
        __builtin_amdgcn_s_barrier();     // all waves: tile-t in LDS, iter t-1 reads done
        __builtin_amdgcn_sched_barrier(0);
        if (t + 2 < nt) STAGE_TB(t + 2, (t + 2) % 3);  // into slot freed at iter t-1
        unsigned short* As = smem + (t % 3) * 8192;
        unsigned short* Bs = As + 4096;
        short8 af[4], bf[4];
        int q8 = (lane >> 4) * 8;
#pragma unroll
        for (int i = 0; i < 4; ++i) {
            int m = wr * 64 + i * 16 + (lane & 15);
            af[i] = *(const short8*)&As[m * 32 + q8];
            int n = wc * 64 + i * 16 + (lane & 15);
            bf[i] = *(const short8*)&Bs[n * 32 + q8];
        }
#pragma unroll
        for (int i = 0; i < 4; ++i)
#pragma unroll
            for (int j = 0; j < 4; ++j)
                acc[i][j] = __builtin_amdgcn_mfma_f32_16x16x32_bf16(af[i], bf[j], acc[i][j], 0, 0, 0);
    }
#undef STAGE_TB
    __syncthreads();   // all waves done reading LDS before epilogue reuses it
    if (C8) {
        store_fp8_tile(row0, col0, tid, smem, acc, bias, C8, wr, wc, lane);
        return;
    }
    int q = lane >> 4;
    int cn = lane & 15;
#pragma unroll
    for (int j = 0; j < 4; ++j) {
        int col = col0 + wc * 64 + j * 16 + cn;
        float bv = bias[col];
#pragma unroll
        for (int i = 0; i < 4; ++i) {
            int rowb = row0 + wr * 64 + i * 16 + q * 4;
#pragma unroll
            for (int r = 0; r < 4; ++r) {
                float vv = fmaxf(acc[i][j][r] + bv, 0.f);
                C[(size_t)(rowb + r) * HID_D + col] = f2bf(vv);
            }
        }
    }
}

// two independent gemms (different graphs) in one launch (counted-vmcnt body)
__launch_bounds__(256)
__global__ void gemm_pair(const unsigned short* __restrict__ A1,
                          const unsigned short* __restrict__ W1,
                          const float* __restrict__ b1,
                          unsigned short* __restrict__ C1, unsigned char* C81, int K1,
                          const unsigned short* __restrict__ A2,
                          const unsigned short* __restrict__ W2,
                          const float* __restrict__ b2,
                          unsigned short* __restrict__ C2, unsigned char* C82, int K2) {
    __shared__ unsigned short smem[24576];
    int b = blockIdx.x;
    int bx, by;
    if (b < NGEMM) {
        gmap(b, bx, by);
        gemm_body_tb(bx, by, threadIdx.x, smem, A1, W1, b1, C1, C81, K1);
    } else {
        gmap(b - NGEMM, bx, by);
        gemm_body_tb(bx, by, threadIdx.x, smem, A2, W2, b2, C2, C82, K2);
    }
}

// ---------------- fused: gemm blocks first, fp8-agg blocks after ---------------
template<int LPR4, int NSLAB>
__launch_bounds__(256)
__global__ void fused_k(const unsigned short* __restrict__ A,
                        const unsigned short* __restrict__ Wt,
                        const float* __restrict__ bias,
                        unsigned short* __restrict__ C, unsigned char* C8, int K,
                        const unsigned char* __restrict__ x8,
                        const int* __restrict__ row_start,
                        const unsigned short* __restrict__ csr,
                        unsigned short* __restrict__ h, int n0, int nGemm) {
    __shared__ unsigned short smem[16384];
    int b = blockIdx.x;
    if (b < nGemm) {
        int bx, by;
        gmap(b, bx, by);
        gemm_body_db(bx, by, threadIdx.x, smem, A, Wt, bias, C, C8, K);
    } else {
        agg8_body<LPR4, NSLAB>(b - nGemm, threadIdx.x, x8, row_start, csr, h, n0);
    }
}

// ---------------- final linear [M,512]bf16 @ [512,2]fp32 + b ----------------
__device__ __forceinline__ void lin_body(int bb, int tid, const unsigned short* __restrict__ A,
                                         const float* __restrict__ w, const float* __restrict__ b,
                                         float* __restrict__ o, int M) {
    int wave = tid >> 6;
    int lane = tid & 63;
    int row = bb * 4 + wave;
    if (row >= M) return;
    const uint4* Ar = (const uint4*)(A + (size_t)row * 512);
    uint4 u = Ar[lane];
    float f[8];
    f[0] = bflo(u.x); f[1] = bfhi(u.x); f[2] = bflo(u.y); f[3] = bfhi(u.y);
    f[4] = bflo(u.z); f[5] = bfhi(u.z); f[6] = bflo(u.w); f[7] = bfhi(u.w);
    float s0 = 0.f, s1 = 0.f;
#pragma unroll
    for (int j = 0; j < 8; ++j) {
        int base = (lane * 8 + j) * 2;
        s0 = fmaf(f[j], w[base + 0], s0);
        s1 = fmaf(f[j], w[base + 1], s1);
    }
#pragma unroll
    for (int off = 32; off > 0; off >>= 1) {
        s0 += __shfl_down(s0, off, 64);
        s1 += __shfl_down(s1, off, 64);
    }
    if (lane == 0) { o[row * 2] = s0 + b[0]; o[row * 2 + 1] = s1 + b[1]; }
}

// s10: G32(g2) || lin(g1)  (counted-vmcnt gemm body)
__launch_bounds__(256)
__global__ void fused_gemmlin(const unsigned short* __restrict__ A,
                              const unsigned short* __restrict__ Wt,
                              const float* __restrict__ bias,
                              unsigned short* __restrict__ C, int K,
                              const unsigned short* __restrict__ L,
                              const float* __restrict__ lw, const float* __restrict__ lb,
                              float* __restrict__ o) {
    __shared__ unsigned short smem[24576];
    int b = blockIdx.x;
    if (b < NGEMM) {
        int bx, by;
        gmap(b, bx, by);
        gemm_body_tb(bx, by, threadIdx.x, smem, A, Wt, bias, C, nullptr, K);
    } else {
        lin_body(b - NGEMM, threadIdx.x, L, lw, lb, o, N1);
    }
}

// s11: lin(g2) + dist
__global__ void lin_dist_kernel(const unsigned short* __restrict__ A,
                                const float* __restrict__ w, const float* __restrict__ b,
                                const float* __restrict__ o1,
                                float* __restrict__ o2out,
                                float* __restrict__ dist) {
    int tid = threadIdx.x;
    int wave = tid >> 6;
    int lane = tid & 63;
    int row = blockIdx.x * 4 + wave;
    if (row >= N1) return;
    const uint4* Ar = (const uint4*)(A + (size_t)row * 512);
    uint4 u = Ar[lane];
    float f[8];
    f[0] = bflo(u.x); f[1] = bfhi(u.x); f[2] = bflo(u.y); f[3] = bfhi(u.y);
    f[4] = bflo(u.z); f[5] = bfhi(u.z); f[6] = bflo(u.w); f[7] = bfhi(u.w);
    float s0 = 0.f, s1 = 0.f;
#pragma unroll
    for (int j = 0; j < 8; ++j) {
        int base = (lane * 8 + j) * 2;
        s0 = fmaf(f[j], w[base + 0], s0);
        s1 = fmaf(f[j], w[base + 1], s1);
    }
#pragma unroll
    for (int off = 32; off > 0; off >>= 1) {
        s0 += __shfl_down(s0, off, 64);
        s1 += __shfl_down(s1, off, 64);
    }
    if (lane == 0) {
        float vx = s0 + b[0], vy = s1 + b[1];
        o2out[row * 2] = vx; o2out[row * 2 + 1] = vy;
        float2 a = ((const float2*)o1)[row];
        float d0 = a.x - vx + 1e-6f, d1 = a.y - vy + 1e-6f;
        dist[row] = sqrtf(d0 * d0 + d1 * d1);
    }
}

// LDS-privatized histogram
#define HBLK 20
#define HPB  1000
__launch_bounds__(256)
__global__ void hist_lds_kernel(const float* __restrict__ dist, int* __restrict__ hist) {
    __shared__ int lh[4096];
    int t = threadIdx.x;
    for (int i = t; i < 4096; i += 256) lh[i] = 0;
    __syncthreads();
    int base = blockIdx.x * HPB;
    for (int i = t; i < HPB; i += 256) {
        int idx = base + i;
        if (idx < N1) atomicAdd(&lh[__float_as_uint(dist[idx]) >> 19], 1);
    }
    __syncthreads();
    for (int i = t; i < 4096; i += 256) {
        int v = lh[i];
        if (v) atomicAdd(&hist[i], v);
    }
}

// ---------------- radix-select top-k ----------------
__global__ void selk_kernel(const int* __restrict__ hist, int* __restrict__ selout) {
    __shared__ int tile[256];
    int t = threadIdx.x;
    int running = 0;
    for (int tb = 0; tb < 16; ++tb) {
        int idx = 4095 - (tb * 256 + t);
        int v = hist[idx];
        tile[t] = v;
        __syncthreads();
        for (int off = 1; off < 256; off <<= 1) {
            int x = (t >= off) ? tile[t - off] : 0;
            __syncthreads();
            tile[t] += x;
            __syncthreads();
        }
        int incl = running + tile[t];
        if (incl >= TOPK && incl - v < TOPK) selout[0] = idx;
        running += tile[255];
        __syncthreads();
        if (running >= TOPK) break;
    }
}

__global__ void compact_kernel(const float* __restrict__ dist, const int* __restrict__ selout,
                               int* __restrict__ nc, float* __restrict__ cd, int* __restrict__ ci) {
    int i = blockIdx.x * blockDim.x + threadIdx.x;
    if (i >= N1) return;
    float d = dist[i];
    int b = (int)(__float_as_uint(d) >> 19);
    if (b >= selout[0]) {
        int p = atomicAdd(nc, 1);
        cd[p] = d;
        ci[p] = i;
    }
}

#define CCH 2048
__global__ void rankc_kernel(const float* __restrict__ cd, const int* __restrict__ ci,
                             const int* __restrict__ nc_p, float* __restrict__ vals) {
    __shared__ float ds[CCH];
    __shared__ int   di_[CCH];
    int nc = *nc_p;
    if (blockIdx.x * 256 >= nc) return;
    int t = threadIdx.x;
    int q = blockIdx.x * 256 + t;
    float dq = 0.f; int iq = 0;
    if (q < nc) { dq = cd[q]; iq = ci[q]; }
    int cnt = 0;
    for (int c0 = 0; c0 < nc; c0 += CCH) {
        int lim = min(CCH, nc - c0);
        for (int j = t; j < lim; j += 256) { ds[j] = cd[c0 + j]; di_[j] = ci[c0 + j]; }
        __syncthreads();
        if (q < nc) {
            for (int j = 0; j < lim; ++j) {
                float dj = ds[j];
                cnt += (dj > dq) || (dj == dq && di_[j] < iq);
            }
        }
        __syncthreads();
    }
    if (q < nc && cnt < TOPK) vals[cnt] = dq;
}

// ---------------- head MLP (fc1 split 4-way) ----------------
__launch_bounds__(512)
__global__ void head_kernel(const float* __restrict__ vals,
                            const float* __restrict__ fc1_w, const float* __restrict__ fc1_b,
                            const float* __restrict__ ln1_g, const float* __restrict__ ln1_b,
                            const float* __restrict__ fc2_w, const float* __restrict__ fc2_b,
                            const float* __restrict__ ln2_g, const float* __restrict__ ln2_b,
                            const float* __restrict__ fc3_w, const float* __restrict__ fc3_b,
                            float* __restrict__ out) {
    __shared__ float sv[TOPK];
    __shared__ float a1[128];
    __shared__ float red[512];
    __shared__ float s_m, s_r;
    int t = threadIdx.x;
    for (int i = t; i < TOPK; i += 512) sv[i] = vals[i];
    __syncthreads();
    int g = t >> 7, c = t & 127;
    float part = 0.f;
    for (int j = g * 250; j < g * 250 + 250; ++j)
        part = fmaf(sv[j], fc1_w[j * 128 + c], part);
    red[t] = part;
    __syncthreads();
    float h1 = 0.f;
    if (t < 128) h1 = fc1_b[t] + red[t] + red[t + 128] + red[t + 256] + red[t + 384];
    __syncthreads();
    red[t] = (t < 128) ? h1 : 0.f; __syncthreads();
    for (int s = 256; s > 0; s >>= 1) { if (t < s) red[t] += red[t + s]; __syncthreads(); }
    if (t == 0) s_m = red[0] / 128.f;
    __syncthreads();
    float m1 = s_m;
    float dv = (t < 128) ? (h1 - m1) : 0.f;
    red[t] = dv * dv; __syncthreads();
    for (int s = 256; s > 0; s >>= 1) { if (t < s) red[t] += red[t + s]; __syncthreads(); }
    if (t == 0) s_r = rsqrtf(red[0] / 128.f + 1e-5f);
    __syncthreads();
    float r1 = s_r;
    if (t < 128) a1[t] = fmaxf((h1 - m1) * r1 * ln1_g[t] + ln1_b[t], 0.f);
    __syncthreads();
    float h2 = fc2_b[t];
    for (int j = 0; j < 128; ++j) h2 = fmaf(a1[j], fc2_w[j * 512 + t], h2);
    red[t] = h2; __syncthreads();
    for (int s = 256; s > 0; s >>= 1) { if (t < s) red[t] += red[t + s]; __syncthreads(); }
    if (t == 0) s_m = red[0] / 512.f;
    __syncthreads();
    float m2 = s_m;
    float d2 = h2 - m2;
    red[t] = d2 * d2; __syncthreads();
    for (int s = 256; s > 0; s >>= 1) { if (t < s) red[t] += red[t + s]; __syncthreads(); }
    if (t == 0) s_r = rsqrtf(red[0] / 512.f + 1e-5f);
    __syncthreads();
    float r2 = s_r;
    float y2 = fmaxf((h2 - m2) * r2 * ln2_g[t] + ln2_b[t], 0.f);
    red[t] = y2 * fc3_w[t]; __syncthreads();
    for (int s = 256; s > 0; s >>= 1) { if (t < s) red[t] += red[t + s]; __syncthreads(); }
    if (t == 0) out[0] = 1.f / (1.f + expf(-(red[0] + fc3_b[0])));
}

extern "C" void kernel_launch(void* const* d_in, const int* in_sizes, int n_in,
                              void* d_out, int out_size, void* d_ws, size_t ws_size,
                              hipStream_t stream) {
    const float* x1   = (const float*)d_in[0];
    const int*   ei1  = (const int*)d_in[1];
    const float* x2   = (const float*)d_in[2];
    const int*   ei2  = (const int*)d_in[3];
    const float* w11  = (const float*)d_in[4];
    const float* b11  = (const float*)d_in[5];
    const float* w12  = (const float*)d_in[6];
    const float* b12  = (const float*)d_in[7];
    const float* w21  = (const float*)d_in[8];
    const float* b21  = (const float*)d_in[9];
    const float* w22  = (const float*)d_in[10];
    const float* b22  = (const float*)d_in[11];
    const float* w31  = (const float*)d_in[12];
    const float* b31  = (const float*)d_in[13];
    const float* w32  = (const float*)d_in[14];
    const float* b32  = (const float*)d_in[15];
    const float* lw   = (const float*)d_in[16];
    const float* lb   = (const float*)d_in[17];
    const float* fc1w = (const float*)d_in[18];
    const float* fc1b = (const float*)d_in[19];
    const float* ln1g = (const float*)d_in[20];
    const float* ln1b = (const float*)d_in[21];
    const float* fc2w = (const float*)d_in[22];
    const float* fc2b = (const float*)d_in[23];
    const float* ln2g = (const float*)d_in[24];
    const float* ln2b = (const float*)d_in[25];
    const float* fc3w = (const float*)d_in[26];
    const float* fc3b = (const float*)d_in[27];

    char* ws = (char*)d_ws;
    size_t off = 0;
    auto alloc = [&](size_t bytes) -> void* {
        void* p = ws + off;
        off += (bytes + 255) & ~(size_t)255;
        return p;
    };
    unsigned char*  XB8 = (unsigned char*)alloc((size_t)NT * FIN_D);       // fp8 inputs
    unsigned short* H0a = (unsigned short*)alloc((size_t)MP1 * HID_D * 2);
    unsigned short* H1a = (unsigned short*)alloc((size_t)MP1 * HID_D * 2);
    unsigned short* H0b = (unsigned short*)alloc((size_t)MP1 * HID_D * 2);
    unsigned short* H1b = (unsigned short*)alloc((size_t)MP1 * HID_D * 2);
    unsigned char*  F8a = (unsigned char*)alloc((size_t)MP1 * HID_D);      // fp8 agg tables
    unsigned char*  F8b = (unsigned char*)alloc((size_t)MP1 * HID_D);
    unsigned short* wt11 = (unsigned short*)alloc((size_t)HID_D * FIN_D * 2);
    unsigned short* wt12 = (unsigned short*)alloc((size_t)HID_D * HID_D * 2);
    unsigned short* wt21 = (unsigned short*)alloc((size_t)HID_D * HID_D * 2);
    unsigned short* wt22 = (unsigned short*)alloc((size_t)HID_D * HID_D * 2);
    unsigned short* wt31 = (unsigned short*)alloc((size_t)HID_D * HID_D * 2);
    unsigned short* wt32 = (unsigned short*)alloc((size_t)HID_D * HID_D * 2);
    float* o         = (float*)alloc((size_t)NT * 2 * 4);
    float* dist      = (float*)alloc((size_t)N1 * 4);
    float* vals      = (float*)alloc((size_t)TOPK * 4);
    int*   row_start = (int*)alloc((size_t)(NT + 1) * 4);
    unsigned short* csr16 = (unsigned short*)alloc((size_t)ET * 2);
    unsigned int* stageG  = (unsigned int*)alloc((size_t)NB * CAP * 4);    // 6.4MB bucket staging
    int*   gcnt      = (int*)alloc((size_t)160 * 4);
    int*   selblk    = (int*)alloc((size_t)(4096 + 64) * 4);
    int*   hist      = selblk;
    int*   nc        = selblk + 4096;
    int*   selout    = (int*)alloc(2 * 4);
    float* cd        = (float*)alloc((size_t)N1 * 4);
    int*   ci        = (int*)alloc((size_t)N1 * 4);

    const unsigned char* XB8g2 = XB8 + (size_t)N1 * FIN_D;

    // ---- pipelined prep: nothing latency-bound runs naked ----
    hipMemsetAsync(gcnt, 0, 160 * sizeof(int), stream);
    hipMemsetAsync(selblk, 0, (4096 + 64) * sizeof(int), stream);
    // k1: bucketA || convx(g1)
    prep1_kernel<<<NB + 5000, 256, 0, stream>>>(ei1, ei2, stageG, gcnt, x1, XB8);
    // k2: sort(all buckets) || convx(g2)
    fused_sortx<<<NB + 5000, 256, 0, stream>>>(stageG, gcnt, row_start, csr16,
                                               x2, (unsigned char*)XB8g2);
    // k3: agg1(g1) || 6x convw  (4.2KB LDS -> full agg residency)
    fused_aggw<<<AGG256 + 1408, 256, 0, stream>>>(
        XB8, row_start, csr16, H0a,
        w11, wt11, w12, wt12, w21, wt21, w22, wt22, w31, wt31, w32, wt32);

    // ---- staggered two-graph pipeline ----
    // s2: G11(g1) bf16 || agg1(g2) fp8
    fused_k<16, 2><<<NGEMM + AGG256, 256, 0, stream>>>(H0a, wt11, b11, H1a, nullptr, FIN_D,
                                                       XB8g2, row_start, csr16, H0b, N1, NGEMM);
    // s3: G12(g1)->fp8 F8a + G11(g2)->bf16 H1b
    gemm_pair<<<2 * NGEMM, 256, 0, stream>>>(H1a, wt12, b12, nullptr, F8a, HID_D,
                                             H0b, wt11, b11, H1b, nullptr, FIN_D);
    // s4: G12(g2)->fp8 F8b || agg2(g1): F8a -> H1a
    fused_k<32, 4><<<NGEMM + AGG512, 256, 0, stream>>>(H1b, wt12, b12, nullptr, F8b, HID_D,
                                                       F8a, row_start, csr16, H1a, 0, NGEMM);
    // s5: G21(g1): H1a -> H0a || agg2(g2): F8b -> H1b
    fused_k<32, 4><<<NGEMM + AGG512, 256, 0, stream>>>(H1a, wt21, b21, H0a, nullptr, HID_D,
                                                       F8b, row_start, csr16, H1b, N1, NGEMM);
    // s6: G22(g1)->fp8 F8a + G21(g2): H1b -> H0b
    gemm_pair<<<2 * NGEMM, 256, 0, stream>>>(H0a, wt22, b22, nullptr, F8a, HID_D,
                                             H1b, wt21, b21, H0b, nullptr, HID_D);
    // s7: G22(g2)->fp8 F8b || agg3(g1): F8a -> H1a
    fused_k<32, 4><<<NGEMM + AGG512, 256, 0, stream>>>(H0b, wt22, b22, nullptr, F8b, HID_D,
                                                       F8a, row_start, csr16, H1a, 0, NGEMM);
    // s8: G31(g1): H1a -> H0a || agg3(g2): F8b -> H1b
    fused_k<32, 4><<<NGEMM + AGG512, 256, 0, stream>>>(H1a, wt31, b31, H0a, nullptr, HID_D,
                                                       F8b, row_start, csr16, H1b, N1, NGEMM);
    // s9: G32(g1): H0a -> H1a + G31(g2): H1b -> H0b
    gemm_pair<<<2 * NGEMM, 256, 0, stream>>>(H0a, wt32, b32, H1a, nullptr, HID_D,
                                             H1b, wt31, b31, H0b, nullptr, HID_D);
    // s10: G32(g2): H0b -> H1b || lin(g1) reads H1a
    fused_gemmlin<<<NGEMM + (N1 + 3) / 4, 256, 0, stream>>>(H0b, wt32, b32, H1b, HID_D,
                                                            H1a, lw, lb, o);
    // s11: lin(g2) + dist
    lin_dist_kernel<<<(N1 + 3) / 4, 256, 0, stream>>>(H1b, lw, lb, o,
                                                      o + 2 * (size_t)N1, dist);
    // s12: LDS-privatized histogram
    hist_lds_kernel<<<HBLK, 256, 0, stream>>>(dist, hist);

    // ---- radix-select top-k + head ----
    selk_kernel<<<1, 256, 0, stream>>>(hist, selout);
    compact_kernel<<<(N1 + 255) / 256, 256, 0, stream>>>(dist, selout, nc, cd, ci);
    rankc_kernel<<<(N1 + 255) / 256, 256, 0, stream>>>(cd, ci, nc, vals);
    head_kernel<<<1, 512, 0, stream>>>(vals, fc1w, fc1b, ln1g, ln1b,
                                       fc2w, fc2b, ln2g, ln2b, fc3w, fc3b,
                                       (float*)d_out);
}